// Round 5
// baseline (3999.249 us; speedup 1.0000x reference)
//
#include <hip/hip_runtime.h>
#include <hip/hip_bf16.h>
#include <cstdint>
#include <cstddef>

// Model: B=1024, S=60, CIN=25, D=256, H=256, T=S+2=62
// Inputs fp32, output fp32; internal bf16 activations/weights, fp32 accum.
//
// Round-16 = R14 (best verified, 1412us) + two contained trims:
//  (1) exchange tail: bar(drain) -> tid0 post; per-wave lane0 poll; per-wave
//      pull of its 2 rows; ONE barrier. Read-vs-write slack identical to R14
//      (reads only after partner's drained post) -- avoids R15's coherence
//      storm (R15 evidence: dur == hbm_bytes/480GB/s, FETCH 3.4x).
//  (2) weight tail LDS-resident: last 4 (L0) / 3 (L1) per-wave weight blocks
//      cached in LDS once (prologue), read via ds_read_b128 every step on
//      the LDS port -- stream drops 16->12 / 24->21 blocks through the
//      ~115 GB/s/CU L1-return wall. Biases move to registers (LDS budget:
//      L0 156.4KB, L1 140KB; R12 proved >64KB static LDS works).

typedef __attribute__((ext_vector_type(8))) short short8;
typedef __attribute__((ext_vector_type(4))) float floatx4;

#define BATCH 1024
#define TSTEPS 62

__device__ __forceinline__ float bf2f(short s) {
    union { unsigned u; float f; } v;
    v.u = ((unsigned)(unsigned short)s) << 16;
    return v.f;
}
__device__ __forceinline__ short f2bf(float f) {
    union { float f; unsigned u; } v; v.f = f;
    unsigned r = (v.u + 0x7fffu + ((v.u >> 16) & 1u)) >> 16;  // RNE
    return (short)r;
}
__device__ __forceinline__ float sigf(float x) {
    return __builtin_amdgcn_rcpf(1.0f + __expf(-x));
}
__device__ __forceinline__ float tanhf_fast(float x) {
    return 2.0f * __builtin_amdgcn_rcpf(1.0f + __expf(-2.0f * x)) - 1.0f;
}

// async 16B/lane global->LDS (LDS dest = uniform base + lane*16)
__device__ __forceinline__ void load_lds16(const short* g, short* l) {
    __builtin_amdgcn_global_load_lds(
        (const __attribute__((address_space(1))) void*)g,
        (__attribute__((address_space(3))) void*)l, 16, 0, 0);
}

// ------------- repack [Wih|Whh] into unit-split wave-blocked layout --------
// dst idx = ((((dh*8 + w)*KB + kb)*4 + g)*64 + lane)*8 + j
//   dh = dir*2 + half
//   row = g*256 + half*128 + w*16 + (lane&15)
//   k   = kb*32 + (lane>>4)*8 + j
__global__ __launch_bounds__(256) void repack_kernel(
    const float* __restrict__ Wih, const float* __restrict__ Whh,
    short* __restrict__ Wp, int XI)
{
    const int KB = (XI + 256) / 32;
    int idx = blockIdx.x * 256 + threadIdx.x;
    if (idx >= 8 * KB * 8192) return;
    int j    = idx & 7;
    int lane = (idx >> 3) & 63;
    int g    = (idx >> 9) & 3;
    int rem  = idx >> 11;
    int kb   = rem % KB;
    int rem2 = rem / KB;
    int w    = rem2 & 7;
    int dh   = rem2 >> 3;       // 0..3
    int dir  = dh >> 1;
    int half = dh & 1;
    int row  = g * 256 + half * 128 + w * 16 + (lane & 15);
    int k    = kb * 32 + (lane >> 4) * 8 + j;
    float v = (k < XI) ? Wih[((size_t)dir * 1024 + row) * XI + k]
                       : Whh[((size_t)dir * 1024 + row) * 256 + (k - XI)];
    Wp[idx] = f2bf(v);
}

// ---------------- embed: seq[t][b][d], row stride 264 ----------------------
__global__ __launch_bounds__(256) void embed_kernel(
    const float* __restrict__ x, const float* __restrict__ Wg,
    const float* __restrict__ bg, const float* __restrict__ Wl,
    const float* __restrict__ bl, short* __restrict__ seq)
{
    const int b = blockIdx.x;
    const int d = threadIdx.x;  // 256 = D
    __shared__ float xs[1500];
    for (int i = d; i < 1500; i += 256) xs[i] = x[(size_t)b * 1500 + i];
    __syncthreads();

    float g = bg[d];
#pragma unroll
    for (int c = 0; c < 16; ++c) g += xs[9 + c] * Wg[d * 16 + c];
    short gb = f2bf(g);
    seq[((size_t)0 * BATCH + b) * 264 + d] = gb;
    seq[((size_t)61 * BATCH + b) * 264 + d] = gb;

    for (int t = 0; t < 60; ++t) {
        float v = bl[d];
#pragma unroll
        for (int c = 0; c < 9; ++c) v += xs[t * 25 + c] * Wl[d * 9 + c];
        seq[((size_t)(t + 1) * BATCH + b) * 264 + d] = f2bf(v);
    }
}

// ---------------- persistent biLSTM layer (unit-split, 256 WGs) ------------
#define LOADW(BUF, kbq)                                                          \
    {                                                                            \
        _Pragma("unroll")                                                        \
        for (int g = 0; g < 4; ++g)                                              \
            BUF[g] = *reinterpret_cast<const short8*>(                           \
                wpb + (size_t)(kbq) * 2048 + g * 512);                           \
    }
#define LOADWL(BUF, i)                                                           \
    {                                                                            \
        _Pragma("unroll")                                                        \
        for (int g = 0; g < 4; ++g)                                              \
            BUF[g] = *reinterpret_cast<const short8*>(                           \
                &w_lds[wv][(i) * 2048 + g * 512 + lane * 8]);                    \
    }
#define LOADA(DST, kbg)                                                          \
    {                                                                            \
        DST = ((kbg) < XB)                                                       \
            ? *reinterpret_cast<const short8*>(xs_cur + lr * (XI + 8) + (kbg) * 32 + quad * 8) \
            : *reinterpret_cast<const short8*>(&h_lds[lr][((kbg) - XB) * 32 + quad * 8]); \
    }
#define MFMA4(AV, BUF)                                                           \
    {                                                                            \
        _Pragma("unroll")                                                        \
        for (int g = 0; g < 4; ++g)                                              \
            acc[g] = __builtin_amdgcn_mfma_f32_16x16x32_bf16(                    \
                AV, BUF[g], acc[g], 0, 0, 0);                                    \
    }
// stage one 16-row X tile (XI cols of XSTR-stride rows): 8 waves x 2 rows
#define STAGE(BUFP, T1)                                                          \
    {                                                                            \
        const short* xtb = X + ((size_t)(T1) * BATCH + bbase) * XSTR;            \
        _Pragma("unroll")                                                        \
        for (int i = 0; i < 2; ++i) {                                            \
            int row = wv * 2 + i;                                                \
            if (XI == 512 || lane < 32)                                          \
                load_lds16(xtb + (size_t)row * XSTR + lane * 8,                  \
                           (BUFP) + row * (XI + 8));                             \
        }                                                                        \
    }

template <int KK, int XSTR, int OSTR>  // KK=512: XI=256 (layer0); KK=768: XI=512
__global__ __launch_bounds__(512, 2) void lstm_fused_kernel(
    const short* __restrict__ X,      // (62,1024,XSTR) bf16, first XI cols used
    const short* __restrict__ Wcat,   // unit-split wave-blocked [Wih|Whh]
    const float* __restrict__ bih, const float* __restrict__ bhh,
    short* __restrict__ Hout,         // (62,1024,OSTR); dir d -> cols [256d,..)
    int* __restrict__ flags)          // (pair,half) flags, padded x16 ints
{
    constexpr int XI  = KK - 256;
    constexpr int KB  = KK / 32;              // 16 or 24
    constexpr int XB  = XI / 32;              // 8 or 16
    constexpr int WLB = (XI == 256) ? 4 : 3;  // LDS-resident tail blocks/wave
    constexpr int S   = KB - WLB;             // streamed blocks: 12 or 21

    const int wg    = blockIdx.x;     // 256 = (2 halves) x (2 dirs x 64 tiles)
    const int half  = wg >> 7;
    const int pair  = wg & 127;       // dir*64 + tile
    const int dir   = pair >> 6;
    const int bbase = (pair & 63) * 16;
    const int tid   = threadIdx.x;
    const int wv    = tid >> 6;       // 0..7
    const int lane  = tid & 63;
    const int quad  = lane >> 4;
    const int lr    = lane & 15;

    __shared__ __align__(16) short h_lds[16][264];
    __shared__ __align__(16) short x_stage[2][16 * (XI + 8)];
    __shared__ __align__(16) short w_lds[8][WLB * 2048];
    for (int i = tid; i < 16 * 264; i += 512) (&h_lds[0][0])[i] = 0;

    // per-wave weight stream: KB blocks of 2048 shorts (4 gates x 512)
    const short* wpb = Wcat +
        ((size_t)((dir * 2 + half) * 8 + wv) * KB) * 2048 + lane * 8;

    // prologue: copy the last WLB weight blocks into LDS (read every step)
#pragma unroll
    for (int i = 0; i < WLB; ++i)
#pragma unroll
        for (int g = 0; g < 4; ++g)
            *reinterpret_cast<short8*>(&w_lds[wv][i * 2048 + g * 512 + lane * 8]) =
                *reinterpret_cast<const short8*>(
                    wpb + (size_t)(S + i) * 2048 + g * 512);

    // biases in registers (4 per thread, all gates of this thread's unit)
    const int unit = half * 128 + wv * 16 + lr;
    const float bi  = bih[dir * 1024 + 0 * 256 + unit] + bhh[dir * 1024 + 0 * 256 + unit];
    const float bf_ = bih[dir * 1024 + 1 * 256 + unit] + bhh[dir * 1024 + 1 * 256 + unit];
    const float bg_ = bih[dir * 1024 + 2 * 256 + unit] + bhh[dir * 1024 + 2 * 256 + unit];
    const float bo_ = bih[dir * 1024 + 3 * 256 + unit] + bhh[dir * 1024 + 3 * 256 + unit];

    const int colB = half * 128;
    const int colC = (half ^ 1) * 128;
    const int myf = ((pair << 1) | half) * 16;       // 64B-padded flags
    const int paf = ((pair << 1) | (half ^ 1)) * 16;

    float c_st[4];
#pragma unroll
    for (int r = 0; r < 4; ++r) c_st[r] = 0.0f;

    // prologue: stage X[t0] into buffer 0 (drained by the barrier below)
    {
        const int t0 = dir ? (TSTEPS - 1) : 0;
        STAGE(&x_stage[0][0], t0);
    }
    __syncthreads();

    for (int st = 0; st < TSTEPS; ++st) {
        const int t = dir ? (TSTEPS - 1 - st) : st;
        if (st + 1 < TSTEPS) {
            const int t1 = dir ? (TSTEPS - 2 - st) : (st + 1);
            STAGE(&x_stage[(st + 1) & 1][0], t1);
        }
        const short* xs_cur = &x_stage[st & 1][0];

        floatx4 acc[4];
#pragma unroll
        for (int i = 0; i < 4; ++i) acc[i] = (floatx4){0.f, 0.f, 0.f, 0.f};

        // dist-2 register pipeline over streamed blocks 0..S-1, then the
        // LDS-resident tail (blocks S..KB-1). Loop bound KB-8 (KB%4==0).
        short8 W0[4], W1[4], Y0[4], Y1[4], a0, a1;
        LOADW(W0, 0);
        LOADW(W1, 1);
        LOADA(a0, 0);
#pragma unroll 1
        for (int kb = 0; kb < KB - 8; kb += 4) {
            LOADW(Y0, kb + 2); LOADA(a1, kb + 1); MFMA4(a0, W0);
            LOADW(Y1, kb + 3); LOADA(a0, kb + 2); MFMA4(a1, W1);
            LOADW(W0, kb + 4); LOADA(a1, kb + 3); MFMA4(a0, Y0);
            LOADW(W1, kb + 5); LOADA(a0, kb + 4); MFMA4(a1, Y1);
        }
        if constexpr (XI == 256) {
            // S=12: entering with W0=blk8, W1=blk9, a0=A(8)
            LOADW(Y0, 10);  LOADA(a1, 9);  MFMA4(a0, W0);   // 8
            LOADW(Y1, 11);  LOADA(a0, 10); MFMA4(a1, W1);   // 9
            LOADWL(W0, 0);  LOADA(a1, 11); MFMA4(a0, Y0);   // 10
            LOADWL(W1, 1);  LOADA(a0, 12); MFMA4(a1, Y1);   // 11
            LOADWL(Y0, 2);  LOADA(a1, 13); MFMA4(a0, W0);   // 12 (lds)
            LOADWL(Y1, 3);  LOADA(a0, 14); MFMA4(a1, W1);   // 13 (lds)
            LOADA(a1, 15);  MFMA4(a0, Y0);                  // 14 (lds)
            MFMA4(a1, Y1);                                  // 15 (lds)
        } else {
            // S=21: entering with W0=blk16, W1=blk17, a0=A(16)
            LOADW(Y0, 18);  LOADA(a1, 17); MFMA4(a0, W0);   // 16
            LOADW(Y1, 19);  LOADA(a0, 18); MFMA4(a1, W1);   // 17
            LOADW(W0, 20);  LOADA(a1, 19); MFMA4(a0, Y0);   // 18
            LOADWL(W1, 0);  LOADA(a0, 20); MFMA4(a1, Y1);   // 19
            LOADWL(Y0, 1);  LOADA(a1, 21); MFMA4(a0, W0);   // 20
            LOADWL(Y1, 2);  LOADA(a0, 22); MFMA4(a1, W1);   // 21 (lds)
            LOADA(a1, 23);  MFMA4(a0, Y0);                  // 22 (lds)
            MFMA4(a1, Y1);                                  // 23 (lds)
        }

        __syncthreads();  // (1) all h_lds / x_stage reads of this step done

        // cell update -> own h_lds columns (all 4 gates thread-local)
#pragma unroll
        for (int r = 0; r < 4; ++r) {
            float iv = acc[0][r] + bi;
            float fv = acc[1][r] + bf_;
            float gv = acc[2][r] + bg_;
            float ov = acc[3][r] + bo_;
            float c = sigf(fv) * c_st[r] + sigf(iv) * tanhf_fast(gv);
            c_st[r] = c;
            float h = sigf(ov) * tanhf_fast(c);
            h_lds[quad * 4 + r][unit] = f2bf(h);
        }
        __syncthreads();  // (2) own half complete in h_lds

        // own-half writeback: coalesced agent-scope 8B stores (partner reads)
        {
            const int row = tid >> 5, c4 = tid & 31;
            unsigned long long v = *reinterpret_cast<const unsigned long long*>(
                &h_lds[row][colB + c4 * 4]);
            __hip_atomic_store(
                reinterpret_cast<unsigned long long*>(
                    Hout + ((size_t)t * BATCH + bbase + row) * OSTR +
                    dir * 256 + colB) + c4,
                v, __ATOMIC_RELAXED, __HIP_MEMORY_SCOPE_AGENT);
        }
        __syncthreads();  // (3) stores drained -> safe to publish

        if (st + 1 < TSTEPS) {
            if (tid == 0)
                __hip_atomic_store(&flags[myf], st + 1, __ATOMIC_RELEASE,
                                   __HIP_MEMORY_SCOPE_AGENT);
            // per-wave poll (lane0; wave is lockstep) then per-wave pull of
            // its own 2 rows -- read happens only after partner's drained
            // post (same loose timing as R14; avoids the R15 storm)
            if (lane == 0) {
                while (__hip_atomic_load(&flags[paf], __ATOMIC_ACQUIRE,
                                         __HIP_MEMORY_SCOPE_AGENT) <= st)
                    __builtin_amdgcn_s_sleep(1);
            }
            const int prow = wv * 2 + (lane >> 5);
            const int pc4  = lane & 31;
            unsigned long long v = __hip_atomic_load(
                reinterpret_cast<const unsigned long long*>(
                    Hout + ((size_t)t * BATCH + bbase + prow) * OSTR +
                    dir * 256 + colC) + pc4,
                __ATOMIC_RELAXED, __HIP_MEMORY_SCOPE_AGENT);
            *reinterpret_cast<unsigned long long*>(
                &h_lds[prow][colC + pc4 * 4]) = v;
            __syncthreads();  // (4) partner fill visible to all waves
        }
    }
}

// ---------------- heads (fp32 output; h1 row stride 512) -------------------
__global__ __launch_bounds__(256) void lout_kernel(
    const short* __restrict__ h1, const float* __restrict__ Wlp,
    const float* __restrict__ blp, float* __restrict__ out)
{
    __shared__ float wl[6 * 512];
    for (int i = threadIdx.x; i < 6 * 512; i += 256) wl[i] = Wlp[i];
    __syncthreads();

    int idx = blockIdx.x * 256 + threadIdx.x;
    if (idx >= BATCH * 60) return;
    int b = idx & (BATCH - 1);
    int s = idx >> 10;
    const short* hrow = h1 + ((size_t)(s + 1) * BATCH + b) * 512;

    float acc[6];
#pragma unroll
    for (int j = 0; j < 6; ++j) acc[j] = blp[j];
    for (int k = 0; k < 512; k += 8) {
        short8 hv = *reinterpret_cast<const short8*>(hrow + k);
#pragma unroll
        for (int e = 0; e < 8; ++e) {
            float h = bf2f(hv[e]);
#pragma unroll
            for (int j = 0; j < 6; ++j) acc[j] += h * wl[j * 512 + k + e];
        }
    }
    float* orow = out + ((size_t)b * 60 + s) * 14;
#pragma unroll
    for (int j = 0; j < 6; ++j) orow[j] = acc[j];
}

__global__ __launch_bounds__(256) void gout_kernel(
    const short* __restrict__ h1, const float* __restrict__ Wgp,
    const float* __restrict__ bgp, float* __restrict__ out)
{
    __shared__ float wg[8 * 1024];
    for (int i = threadIdx.x; i < 8 * 1024; i += 256) wg[i] = Wgp[i];
    __syncthreads();

    int b = blockIdx.x * 256 + threadIdx.x;
    if (b >= BATCH) return;
    const short* ha = h1 + (size_t)b * 512;
    const short* hb = h1 + ((size_t)61 * BATCH + b) * 512;

    float acc[8];
#pragma unroll
    for (int j = 0; j < 8; ++j) acc[j] = bgp[j];
    for (int k = 0; k < 512; k += 8) {
        short8 h1v = *reinterpret_cast<const short8*>(ha + k);
        short8 h2v = *reinterpret_cast<const short8*>(hb + k);
#pragma unroll
        for (int e = 0; e < 8; ++e) {
            float v1 = bf2f(h1v[e]);
            float v2 = bf2f(h2v[e]);
#pragma unroll
            for (int j = 0; j < 8; ++j) {
                acc[j] += v1 * wg[j * 1024 + k + e];
                acc[j] += v2 * wg[j * 1024 + 512 + k + e];
            }
        }
    }
    for (int s = 0; s < 60; ++s) {
        float* orow = out + ((size_t)b * 60 + s) * 14 + 6;
#pragma unroll
        for (int j = 0; j < 8; ++j) orow[j] = acc[j];
    }
}

// ---------------- launch ---------------------------------------------------
extern "C" void kernel_launch(void* const* d_in, const int* in_sizes, int n_in,
                              void* d_out, int out_size, void* d_ws, size_t ws_size,
                              hipStream_t stream)
{
    const float* x    = (const float*)d_in[0];
    const float* Wg   = (const float*)d_in[1];
    const float* bg   = (const float*)d_in[2];
    const float* Wl   = (const float*)d_in[3];
    const float* bl   = (const float*)d_in[4];
    const float* Wih0 = (const float*)d_in[5];
    const float* Whh0 = (const float*)d_in[6];
    const float* bih0 = (const float*)d_in[7];
    const float* bhh0 = (const float*)d_in[8];
    const float* Wih1 = (const float*)d_in[9];
    const float* Whh1 = (const float*)d_in[10];
    const float* bih1 = (const float*)d_in[11];
    const float* bhh1 = (const float*)d_in[12];
    const float* Wgp  = (const float*)d_in[13];
    const float* bgp  = (const float*)d_in[14];
    const float* Wlp  = (const float*)d_in[15];
    const float* blp  = (const float*)d_in[16];
    float* out = (float*)d_out;

    const size_t seq_e = (size_t)TSTEPS * BATCH * 264;  // 16,760,832 (stride 264)
    const size_t h0_e  = (size_t)TSTEPS * BATCH * 520;  // 33,013,760 (stride 520)
    const size_t h1_e  = (size_t)TSTEPS * BATCH * 512;  // 32,505,856 (stride 512)
    const size_t cat_e = 8 * 24 * 8192;                 //  1,572,864 (shared, max)
    const size_t cat0_n = 8 * 16 * 8192;                //  layer0 repack count

    short* seq = (short*)d_ws;
    short* h0  = seq + seq_e;
    short* h1  = h0 + h0_e;
    short* cat = h1 + h1_e;
    int*   flags = (int*)(cat + cat_e);   // 2 layers x 256 flags x 16-int pad
    const size_t need = (seq_e + h0_e + h1_e + cat_e) * sizeof(short) + 32768;
    if (ws_size < need) return;

    hipMemsetAsync(flags, 0, 2 * 256 * 16 * sizeof(int), stream);

    embed_kernel<<<BATCH, 256, 0, stream>>>(x, Wg, bg, Wl, bl, seq);

    repack_kernel<<<(int)((cat0_n + 255) / 256), 256, 0, stream>>>(Wih0, Whh0, cat, 256);
    lstm_fused_kernel<512, 264, 520><<<256, 512, 0, stream>>>(seq, cat, bih0, bhh0, h0, flags);

    repack_kernel<<<(int)((cat_e + 255) / 256), 256, 0, stream>>>(Wih1, Whh1, cat, 512);
    lstm_fused_kernel<768, 520, 512><<<256, 512, 0, stream>>>(h0, cat, bih1, bhh1, h1, flags + 256 * 16);

    lout_kernel<<<(BATCH * 60 + 255) / 256, 256, 0, stream>>>(h1, Wlp, blp, out);
    gout_kernel<<<(BATCH + 255) / 256, 256, 0, stream>>>(h1, Wgp, bgp, out);
}

// Round 6
// 1477.932 us; speedup vs baseline: 2.7060x; 2.7060x over previous
//
#include <hip/hip_runtime.h>
#include <hip/hip_bf16.h>
#include <cstdint>
#include <cstddef>

// Model: B=1024, S=60, CIN=25, D=256, H=256, T=S+2=62
// Inputs fp32, output fp32; internal bf16 activations/weights, fp32 accum.
//
// Round-17 = exact R14 structure (best verified, 1412us) + ONE trim:
//   cell update stores its h values DIRECTLY to Hout (2B agent-scope stores,
//   32B granules per quad) instead of a separate LDS-readback+store pass.
//   Removes 1 barrier + 1 LDS round-trip per step. Exchange protocol timing
//   is byte-identical to R14 (drain via next barrier -> post -> poll -> pull)
//   -- the loose slack that avoided R15's coherence storm.
// Session rules learned: (a) weight stream must NEVER go through LDS
// (R12/R16: >128KB-LDS WGs collapse ~3x uniformly); (b) exchange reads must
// stay loose vs partner writes (R15 storm: dur == bytes/480GB/s); (c) one
// change per round.

typedef __attribute__((ext_vector_type(8))) short short8;
typedef __attribute__((ext_vector_type(4))) float floatx4;

#define BATCH 1024
#define TSTEPS 62

__device__ __forceinline__ float bf2f(short s) {
    union { unsigned u; float f; } v;
    v.u = ((unsigned)(unsigned short)s) << 16;
    return v.f;
}
__device__ __forceinline__ short f2bf(float f) {
    union { float f; unsigned u; } v; v.f = f;
    unsigned r = (v.u + 0x7fffu + ((v.u >> 16) & 1u)) >> 16;  // RNE
    return (short)r;
}
__device__ __forceinline__ float sigf(float x) {
    return __builtin_amdgcn_rcpf(1.0f + __expf(-x));
}
__device__ __forceinline__ float tanhf_fast(float x) {
    return 2.0f * __builtin_amdgcn_rcpf(1.0f + __expf(-2.0f * x)) - 1.0f;
}

// async 16B/lane global->LDS (LDS dest = uniform base + lane*16)
__device__ __forceinline__ void load_lds16(const short* g, short* l) {
    __builtin_amdgcn_global_load_lds(
        (const __attribute__((address_space(1))) void*)g,
        (__attribute__((address_space(3))) void*)l, 16, 0, 0);
}

// ------------- repack [Wih|Whh] into unit-split wave-blocked layout --------
// dst idx = ((((dh*8 + w)*KB + kb)*4 + g)*64 + lane)*8 + j
//   dh = dir*2 + half
//   row = g*256 + half*128 + w*16 + (lane&15)
//   k   = kb*32 + (lane>>4)*8 + j
__global__ __launch_bounds__(256) void repack_kernel(
    const float* __restrict__ Wih, const float* __restrict__ Whh,
    short* __restrict__ Wp, int XI)
{
    const int KB = (XI + 256) / 32;
    int idx = blockIdx.x * 256 + threadIdx.x;
    if (idx >= 8 * KB * 8192) return;
    int j    = idx & 7;
    int lane = (idx >> 3) & 63;
    int g    = (idx >> 9) & 3;
    int rem  = idx >> 11;
    int kb   = rem % KB;
    int rem2 = rem / KB;
    int w    = rem2 & 7;
    int dh   = rem2 >> 3;       // 0..3
    int dir  = dh >> 1;
    int half = dh & 1;
    int row  = g * 256 + half * 128 + w * 16 + (lane & 15);
    int k    = kb * 32 + (lane >> 4) * 8 + j;
    float v = (k < XI) ? Wih[((size_t)dir * 1024 + row) * XI + k]
                       : Whh[((size_t)dir * 1024 + row) * 256 + (k - XI)];
    Wp[idx] = f2bf(v);
}

// ---------------- embed: seq[t][b][d], row stride 264 ----------------------
__global__ __launch_bounds__(256) void embed_kernel(
    const float* __restrict__ x, const float* __restrict__ Wg,
    const float* __restrict__ bg, const float* __restrict__ Wl,
    const float* __restrict__ bl, short* __restrict__ seq)
{
    const int b = blockIdx.x;
    const int d = threadIdx.x;  // 256 = D
    __shared__ float xs[1500];
    for (int i = d; i < 1500; i += 256) xs[i] = x[(size_t)b * 1500 + i];
    __syncthreads();

    float g = bg[d];
#pragma unroll
    for (int c = 0; c < 16; ++c) g += xs[9 + c] * Wg[d * 16 + c];
    short gb = f2bf(g);
    seq[((size_t)0 * BATCH + b) * 264 + d] = gb;
    seq[((size_t)61 * BATCH + b) * 264 + d] = gb;

    for (int t = 0; t < 60; ++t) {
        float v = bl[d];
#pragma unroll
        for (int c = 0; c < 9; ++c) v += xs[t * 25 + c] * Wl[d * 9 + c];
        seq[((size_t)(t + 1) * BATCH + b) * 264 + d] = f2bf(v);
    }
}

// ---------------- persistent biLSTM layer (unit-split, 256 WGs) ------------
#define LOADW(BUF, kbq)                                                          \
    {                                                                            \
        _Pragma("unroll")                                                        \
        for (int g = 0; g < 4; ++g)                                              \
            BUF[g] = *reinterpret_cast<const short8*>(                           \
                wpb + (size_t)(kbq) * 2048 + g * 512);                           \
    }
#define LOADA(DST, kbg)                                                          \
    {                                                                            \
        DST = ((kbg) < XB)                                                       \
            ? *reinterpret_cast<const short8*>(xs_cur + lr * (XI + 8) + (kbg) * 32 + quad * 8) \
            : *reinterpret_cast<const short8*>(&h_lds[lr][((kbg) - XB) * 32 + quad * 8]); \
    }
#define MFMA4(AV, BUF)                                                           \
    {                                                                            \
        _Pragma("unroll")                                                        \
        for (int g = 0; g < 4; ++g)                                              \
            acc[g] = __builtin_amdgcn_mfma_f32_16x16x32_bf16(                    \
                AV, BUF[g], acc[g], 0, 0, 0);                                    \
    }
// stage one 16-row X tile (XI cols of XSTR-stride rows): 8 waves x 2 rows
#define STAGE(BUFP, T1)                                                          \
    {                                                                            \
        const short* xtb = X + ((size_t)(T1) * BATCH + bbase) * XSTR;            \
        _Pragma("unroll")                                                        \
        for (int i = 0; i < 2; ++i) {                                            \
            int row = wv * 2 + i;                                                \
            if (XI == 512 || lane < 32)                                          \
                load_lds16(xtb + (size_t)row * XSTR + lane * 8,                  \
                           (BUFP) + row * (XI + 8));                             \
        }                                                                        \
    }

template <int KK, int XSTR, int OSTR>  // KK=512: XI=256 (layer0); KK=768: XI=512
__global__ __launch_bounds__(512, 2) void lstm_fused_kernel(
    const short* __restrict__ X,      // (62,1024,XSTR) bf16, first XI cols used
    const short* __restrict__ Wcat,   // unit-split wave-blocked [Wih|Whh]
    const float* __restrict__ bih, const float* __restrict__ bhh,
    short* __restrict__ Hout,         // (62,1024,OSTR); dir d -> cols [256d,..)
    int* __restrict__ flags)          // 128 pairs x 2 halves, zeroed pre-launch
{
    constexpr int XI = KK - 256;
    constexpr int KB = KK / 32;   // 16 or 24 (divisible by 4)
    constexpr int XB = XI / 32;

    const int wg    = blockIdx.x;     // 256 = (2 halves) x (2 dirs x 64 tiles)
    const int half  = wg >> 7;
    const int pair  = wg & 127;       // dir*64 + tile
    const int dir   = pair >> 6;
    const int bbase = (pair & 63) * 16;
    const int tid   = threadIdx.x;
    const int wv    = tid >> 6;       // 0..7
    const int lane  = tid & 63;
    const int quad  = lane >> 4;
    const int lr    = lane & 15;

    __shared__ __align__(16) short h_lds[16][264];
    __shared__ __align__(16) short x_stage[2][16 * (XI + 8)];
    for (int i = tid; i < 16 * 264; i += 512) (&h_lds[0][0])[i] = 0;

    // per-wave weight stream: KB blocks of 2048 shorts (4 gates x 512)
    const short* wpb = Wcat +
        ((size_t)((dir * 2 + half) * 8 + wv) * KB) * 2048 + lane * 8;

    // biases in registers (all 4 gates of this thread's unit)
    const int unit = half * 128 + wv * 16 + lr;
    const float bi  = bih[dir * 1024 + 0 * 256 + unit] + bhh[dir * 1024 + 0 * 256 + unit];
    const float bf_ = bih[dir * 1024 + 1 * 256 + unit] + bhh[dir * 1024 + 1 * 256 + unit];
    const float bg_ = bih[dir * 1024 + 2 * 256 + unit] + bhh[dir * 1024 + 2 * 256 + unit];
    const float bo_ = bih[dir * 1024 + 3 * 256 + unit] + bhh[dir * 1024 + 3 * 256 + unit];

    const int colC = (half ^ 1) * 128;
    const int myf = (pair << 1) | half;
    const int paf = (pair << 1) | (half ^ 1);

    float c_st[4];
#pragma unroll
    for (int r = 0; r < 4; ++r) c_st[r] = 0.0f;

    // prologue: stage X[t0] into buffer 0 (drained by the barrier below)
    {
        const int t0 = dir ? (TSTEPS - 1) : 0;
        STAGE(&x_stage[0][0], t0);
    }
    __syncthreads();

    for (int st = 0; st < TSTEPS; ++st) {
        const int t = dir ? (TSTEPS - 1 - st) : st;
        if (st + 1 < TSTEPS) {
            const int t1 = dir ? (TSTEPS - 2 - st) : (st + 1);
            STAGE(&x_stage[(st + 1) & 1][0], t1);
        }
        const short* xs_cur = &x_stage[st & 1][0];

        floatx4 acc[4];
#pragma unroll
        for (int i = 0; i < 4; ++i) acc[i] = (floatx4){0.f, 0.f, 0.f, 0.f};

        // 4-buffer distance-2 register pipeline over kb
        short8 W0[4], W1[4], Y0[4], Y1[4], a0, a1;
        LOADW(W0, 0);
        LOADW(W1, 1);
        LOADA(a0, 0);
#pragma unroll 1
        for (int kb = 0; kb < KB - 4; kb += 4) {
            LOADW(Y0, kb + 2); LOADA(a1, kb + 1); MFMA4(a0, W0);
            LOADW(Y1, kb + 3); LOADA(a0, kb + 2); MFMA4(a1, W1);
            LOADW(W0, kb + 4); LOADA(a1, kb + 3); MFMA4(a0, Y0);
            LOADW(W1, kb + 5); LOADA(a0, kb + 4); MFMA4(a1, Y1);
        }
        LOADW(Y0, KB - 2); LOADA(a1, KB - 3); MFMA4(a0, W0);
        LOADW(Y1, KB - 1); LOADA(a0, KB - 2); MFMA4(a1, W1);
        LOADA(a1, KB - 1); MFMA4(a0, Y0);
        MFMA4(a1, Y1);

        __syncthreads();  // (1) all h_lds / x_stage reads of this step done

        // cell update -> h_lds AND direct Hout stores (own columns; 32B
        // granules per quad-row; agent-scope so partner can read after the
        // drain at barrier (2'))
        {
            short* hout_base = Hout + ((size_t)t * BATCH + bbase) * OSTR +
                               dir * 256 + unit;
#pragma unroll
            for (int r = 0; r < 4; ++r) {
                float iv = acc[0][r] + bi;
                float fv = acc[1][r] + bf_;
                float gv = acc[2][r] + bg_;
                float ov = acc[3][r] + bo_;
                float c = sigf(fv) * c_st[r] + sigf(iv) * tanhf_fast(gv);
                c_st[r] = c;
                float h = sigf(ov) * tanhf_fast(c);
                short hb = f2bf(h);
                h_lds[quad * 4 + r][unit] = hb;
                __hip_atomic_store(
                    reinterpret_cast<unsigned short*>(
                        hout_base + (size_t)(quad * 4 + r) * OSTR),
                    (unsigned short)hb, __ATOMIC_RELAXED,
                    __HIP_MEMORY_SCOPE_AGENT);
            }
        }
        __syncthreads();  // (2') h_lds complete + Hout stores drained

        if (st + 1 < TSTEPS) {
            if (tid == 0) {
                __hip_atomic_store(&flags[myf], st + 1, __ATOMIC_RELEASE,
                                   __HIP_MEMORY_SCOPE_AGENT);
                while (__hip_atomic_load(&flags[paf], __ATOMIC_ACQUIRE,
                                         __HIP_MEMORY_SCOPE_AGENT) <= st)
                    __builtin_amdgcn_s_sleep(1);
            }
            __syncthreads();  // (3') partner h(t) visible

            // pull partner half into h_lds
            {
                const int row = tid >> 5, c4 = tid & 31;
                unsigned long long v = __hip_atomic_load(
                    reinterpret_cast<const unsigned long long*>(
                        Hout + ((size_t)t * BATCH + bbase + row) * OSTR +
                        dir * 256 + colC) + c4,
                    __ATOMIC_RELAXED, __HIP_MEMORY_SCOPE_AGENT);
                *reinterpret_cast<unsigned long long*>(
                    &h_lds[row][colC + c4 * 4]) = v;
            }
            __syncthreads();  // (4') h_lds complete for next step
        }
    }
}

// ---------------- heads (fp32 output; h1 row stride 512) -------------------
__global__ __launch_bounds__(256) void lout_kernel(
    const short* __restrict__ h1, const float* __restrict__ Wlp,
    const float* __restrict__ blp, float* __restrict__ out)
{
    __shared__ float wl[6 * 512];
    for (int i = threadIdx.x; i < 6 * 512; i += 256) wl[i] = Wlp[i];
    __syncthreads();

    int idx = blockIdx.x * 256 + threadIdx.x;
    if (idx >= BATCH * 60) return;
    int b = idx & (BATCH - 1);
    int s = idx >> 10;
    const short* hrow = h1 + ((size_t)(s + 1) * BATCH + b) * 512;

    float acc[6];
#pragma unroll
    for (int j = 0; j < 6; ++j) acc[j] = blp[j];
    for (int k = 0; k < 512; k += 8) {
        short8 hv = *reinterpret_cast<const short8*>(hrow + k);
#pragma unroll
        for (int e = 0; e < 8; ++e) {
            float h = bf2f(hv[e]);
#pragma unroll
            for (int j = 0; j < 6; ++j) acc[j] += h * wl[j * 512 + k + e];
        }
    }
    float* orow = out + ((size_t)b * 60 + s) * 14;
#pragma unroll
    for (int j = 0; j < 6; ++j) orow[j] = acc[j];
}

__global__ __launch_bounds__(256) void gout_kernel(
    const short* __restrict__ h1, const float* __restrict__ Wgp,
    const float* __restrict__ bgp, float* __restrict__ out)
{
    __shared__ float wg[8 * 1024];
    for (int i = threadIdx.x; i < 8 * 1024; i += 256) wg[i] = Wgp[i];
    __syncthreads();

    int b = blockIdx.x * 256 + threadIdx.x;
    if (b >= BATCH) return;
    const short* ha = h1 + (size_t)b * 512;
    const short* hb = h1 + ((size_t)61 * BATCH + b) * 512;

    float acc[8];
#pragma unroll
    for (int j = 0; j < 8; ++j) acc[j] = bgp[j];
    for (int k = 0; k < 512; k += 8) {
        short8 h1v = *reinterpret_cast<const short8*>(ha + k);
        short8 h2v = *reinterpret_cast<const short8*>(hb + k);
#pragma unroll
        for (int e = 0; e < 8; ++e) {
            float v1 = bf2f(h1v[e]);
            float v2 = bf2f(h2v[e]);
#pragma unroll
            for (int j = 0; j < 8; ++j) {
                acc[j] += v1 * wg[j * 1024 + k + e];
                acc[j] += v2 * wg[j * 1024 + 512 + k + e];
            }
        }
    }
    for (int s = 0; s < 60; ++s) {
        float* orow = out + ((size_t)b * 60 + s) * 14 + 6;
#pragma unroll
        for (int j = 0; j < 8; ++j) orow[j] = acc[j];
    }
}

// ---------------- launch ---------------------------------------------------
extern "C" void kernel_launch(void* const* d_in, const int* in_sizes, int n_in,
                              void* d_out, int out_size, void* d_ws, size_t ws_size,
                              hipStream_t stream)
{
    const float* x    = (const float*)d_in[0];
    const float* Wg   = (const float*)d_in[1];
    const float* bg   = (const float*)d_in[2];
    const float* Wl   = (const float*)d_in[3];
    const float* bl   = (const float*)d_in[4];
    const float* Wih0 = (const float*)d_in[5];
    const float* Whh0 = (const float*)d_in[6];
    const float* bih0 = (const float*)d_in[7];
    const float* bhh0 = (const float*)d_in[8];
    const float* Wih1 = (const float*)d_in[9];
    const float* Whh1 = (const float*)d_in[10];
    const float* bih1 = (const float*)d_in[11];
    const float* bhh1 = (const float*)d_in[12];
    const float* Wgp  = (const float*)d_in[13];
    const float* bgp  = (const float*)d_in[14];
    const float* Wlp  = (const float*)d_in[15];
    const float* blp  = (const float*)d_in[16];
    float* out = (float*)d_out;

    const size_t seq_e = (size_t)TSTEPS * BATCH * 264;  // 16,760,832 (stride 264)
    const size_t h0_e  = (size_t)TSTEPS * BATCH * 520;  // 33,013,760 (stride 520)
    const size_t h1_e  = (size_t)TSTEPS * BATCH * 512;  // 32,505,856 (stride 512)
    const size_t cat_e = 8 * 24 * 8192;                 //  1,572,864 (shared, max)
    const size_t cat0_n = 8 * 16 * 8192;                //  layer0 repack count

    short* seq = (short*)d_ws;
    short* h0  = seq + seq_e;
    short* h1  = h0 + h0_e;
    short* cat = h1 + h1_e;
    int*   flags = (int*)(cat + cat_e);                 // 2 layers x 256 ints
    const size_t need = (seq_e + h0_e + h1_e + cat_e) * sizeof(short) + 2048;
    if (ws_size < need) return;

    hipMemsetAsync(flags, 0, 2 * 256 * sizeof(int), stream);

    embed_kernel<<<BATCH, 256, 0, stream>>>(x, Wg, bg, Wl, bl, seq);

    repack_kernel<<<(int)((cat0_n + 255) / 256), 256, 0, stream>>>(Wih0, Whh0, cat, 256);
    lstm_fused_kernel<512, 264, 520><<<256, 512, 0, stream>>>(seq, cat, bih0, bhh0, h0, flags);

    repack_kernel<<<(int)((cat_e + 255) / 256), 256, 0, stream>>>(Wih1, Whh1, cat, 512);
    lstm_fused_kernel<768, 520, 512><<<256, 512, 0, stream>>>(h0, cat, bih1, bhh1, h1, flags + 256);

    lout_kernel<<<(BATCH * 60 + 255) / 256, 256, 0, stream>>>(h1, Wlp, blp, out);
    gout_kernel<<<(BATCH + 255) / 256, 256, 0, stream>>>(h1, Wgp, bgp, out);
}

// Round 7
// 1457.776 us; speedup vs baseline: 2.7434x; 1.0138x over previous
//
#include <hip/hip_runtime.h>
#include <hip/hip_bf16.h>
#include <cstdint>
#include <cstddef>

// Model: B=1024, S=60, CIN=25, D=256, H=256, T=S+2=62
// Inputs fp32, output fp32; internal bf16 activations/weights, fp32 accum.
//
// Round-18 = R14 (best verified, 1412us; R17's 2B-store trim regressed and is
// reverted) + ONE change: the partner-h pull becomes an ASYNC global_load_lds
// issued at the tail (2 rows/wave, 16 lanes x 16B, STAGE-proven pattern) and
// completed mid-next-step by a counted s_waitcnt vmcnt(16) + raw s_barrier
// placed in the k-loop right before the first partner-h block
// (SP = XB + (half?0:4), WG-uniform => convergent barrier). The Wih*x phase
// (>=2.2us) hides the pull's IC latency; removes blocking load + ds_write +
// one barrier from the serial tail.
// Safety: partner's h stores are agent-scope (write through to coherence
// point); pulled lines are cold in this CU's caches (each Hout[t] partner
// line touched exactly once per dispatch; dispatch acquire covers re-runs).
// Session rules: weights NEVER via LDS (R12/R16 3x collapse); exchange reads
// stay loose vs writes (R15 storm); one change per round.

typedef __attribute__((ext_vector_type(8))) short short8;
typedef __attribute__((ext_vector_type(4))) float floatx4;

#define BATCH 1024
#define TSTEPS 62

__device__ __forceinline__ float bf2f(short s) {
    union { unsigned u; float f; } v;
    v.u = ((unsigned)(unsigned short)s) << 16;
    return v.f;
}
__device__ __forceinline__ short f2bf(float f) {
    union { float f; unsigned u; } v; v.f = f;
    unsigned r = (v.u + 0x7fffu + ((v.u >> 16) & 1u)) >> 16;  // RNE
    return (short)r;
}
__device__ __forceinline__ float sigf(float x) {
    return __builtin_amdgcn_rcpf(1.0f + __expf(-x));
}
__device__ __forceinline__ float tanhf_fast(float x) {
    return 2.0f * __builtin_amdgcn_rcpf(1.0f + __expf(-2.0f * x)) - 1.0f;
}

// async 16B/lane global->LDS (LDS dest = uniform base + lane*16)
__device__ __forceinline__ void load_lds16(const short* g, short* l) {
    __builtin_amdgcn_global_load_lds(
        (const __attribute__((address_space(1))) void*)g,
        (__attribute__((address_space(3))) void*)l, 16, 0, 0);
}

// ------------- repack [Wih|Whh] into unit-split wave-blocked layout --------
// dst idx = ((((dh*8 + w)*KB + kb)*4 + g)*64 + lane)*8 + j
//   dh = dir*2 + half
//   row = g*256 + half*128 + w*16 + (lane&15)
//   k   = kb*32 + (lane>>4)*8 + j
__global__ __launch_bounds__(256) void repack_kernel(
    const float* __restrict__ Wih, const float* __restrict__ Whh,
    short* __restrict__ Wp, int XI)
{
    const int KB = (XI + 256) / 32;
    int idx = blockIdx.x * 256 + threadIdx.x;
    if (idx >= 8 * KB * 8192) return;
    int j    = idx & 7;
    int lane = (idx >> 3) & 63;
    int g    = (idx >> 9) & 3;
    int rem  = idx >> 11;
    int kb   = rem % KB;
    int rem2 = rem / KB;
    int w    = rem2 & 7;
    int dh   = rem2 >> 3;       // 0..3
    int dir  = dh >> 1;
    int half = dh & 1;
    int row  = g * 256 + half * 128 + w * 16 + (lane & 15);
    int k    = kb * 32 + (lane >> 4) * 8 + j;
    float v = (k < XI) ? Wih[((size_t)dir * 1024 + row) * XI + k]
                       : Whh[((size_t)dir * 1024 + row) * 256 + (k - XI)];
    Wp[idx] = f2bf(v);
}

// ---------------- embed: seq[t][b][d], row stride 264 ----------------------
__global__ __launch_bounds__(256) void embed_kernel(
    const float* __restrict__ x, const float* __restrict__ Wg,
    const float* __restrict__ bg, const float* __restrict__ Wl,
    const float* __restrict__ bl, short* __restrict__ seq)
{
    const int b = blockIdx.x;
    const int d = threadIdx.x;  // 256 = D
    __shared__ float xs[1500];
    for (int i = d; i < 1500; i += 256) xs[i] = x[(size_t)b * 1500 + i];
    __syncthreads();

    float g = bg[d];
#pragma unroll
    for (int c = 0; c < 16; ++c) g += xs[9 + c] * Wg[d * 16 + c];
    short gb = f2bf(g);
    seq[((size_t)0 * BATCH + b) * 264 + d] = gb;
    seq[((size_t)61 * BATCH + b) * 264 + d] = gb;

    for (int t = 0; t < 60; ++t) {
        float v = bl[d];
#pragma unroll
        for (int c = 0; c < 9; ++c) v += xs[t * 25 + c] * Wl[d * 9 + c];
        seq[((size_t)(t + 1) * BATCH + b) * 264 + d] = f2bf(v);
    }
}

// ---------------- persistent biLSTM layer (unit-split, 256 WGs) ------------
#define LOADW(BUF, kbq)                                                          \
    {                                                                            \
        _Pragma("unroll")                                                        \
        for (int g = 0; g < 4; ++g)                                              \
            BUF[g] = *reinterpret_cast<const short8*>(                           \
                wpb + (size_t)(kbq) * 2048 + g * 512);                           \
    }
#define LOADA(DST, kbg)                                                          \
    {                                                                            \
        DST = ((kbg) < XB)                                                       \
            ? *reinterpret_cast<const short8*>(xs_cur + lr * (XI + 8) + (kbg) * 32 + quad * 8) \
            : *reinterpret_cast<const short8*>(&h_lds[lr][((kbg) - XB) * 32 + quad * 8]); \
    }
#define MFMA4(AV, BUF)                                                           \
    {                                                                            \
        _Pragma("unroll")                                                        \
        for (int g = 0; g < 4; ++g)                                              \
            acc[g] = __builtin_amdgcn_mfma_f32_16x16x32_bf16(                    \
                AV, BUF[g], acc[g], 0, 0, 0);                                    \
    }
// stage one 16-row X tile (XI cols of XSTR-stride rows): 8 waves x 2 rows
#define STAGE(BUFP, T1)                                                          \
    {                                                                            \
        const short* xtb = X + ((size_t)(T1) * BATCH + bbase) * XSTR;            \
        _Pragma("unroll")                                                        \
        for (int i = 0; i < 2; ++i) {                                            \
            int row = wv * 2 + i;                                                \
            if (XI == 512 || lane < 32)                                          \
                load_lds16(xtb + (size_t)row * XSTR + lane * 8,                  \
                           (BUFP) + row * (XI + 8));                             \
        }                                                                        \
    }

template <int KK, int XSTR, int OSTR>  // KK=512: XI=256 (layer0); KK=768: XI=512
__global__ __launch_bounds__(512, 2) void lstm_fused_kernel(
    const short* __restrict__ X,      // (62,1024,XSTR) bf16, first XI cols used
    const short* __restrict__ Wcat,   // unit-split wave-blocked [Wih|Whh]
    const float* __restrict__ bih, const float* __restrict__ bhh,
    short* __restrict__ Hout,         // (62,1024,OSTR); dir d -> cols [256d,..)
    int* __restrict__ flags)          // 128 pairs x 2 halves, zeroed pre-launch
{
    constexpr int XI = KK - 256;
    constexpr int KB = KK / 32;   // 16 or 24 (divisible by 4)
    constexpr int XB = XI / 32;   // 8 or 16

    const int wg    = blockIdx.x;     // 256 = (2 halves) x (2 dirs x 64 tiles)
    const int half  = wg >> 7;
    const int pair  = wg & 127;       // dir*64 + tile
    const int dir   = pair >> 6;
    const int bbase = (pair & 63) * 16;
    const int tid   = threadIdx.x;
    const int wv    = tid >> 6;       // 0..7
    const int lane  = tid & 63;
    const int quad  = lane >> 4;
    const int lr    = lane & 15;

    __shared__ __align__(16) short h_lds[16][264];
    __shared__ __align__(16) short x_stage[2][16 * (XI + 8)];
    __shared__ float bias_sh[1024];
    for (int i = tid; i < 16 * 264; i += 512) (&h_lds[0][0])[i] = 0;
    for (int i = tid; i < 1024; i += 512)
        bias_sh[i] = bih[dir * 1024 + i] + bhh[dir * 1024 + i];

    // per-wave weight stream: KB blocks of 2048 shorts (4 gates x 512)
    const short* wpb = Wcat +
        ((size_t)((dir * 2 + half) * 8 + wv) * KB) * 2048 + lane * 8;

    const int colC = (half ^ 1) * 128;
    // first A-block index that reads partner-h columns (colC):
    //   half=0: partner cols 128..255 -> blocks XB+4..XB+7
    //   half=1: partner cols   0..127 -> blocks XB..XB+3
    const int SP = XB + (half ? 0 : 4);
    const int myf = (pair << 1) | half;
    const int paf = (pair << 1) | (half ^ 1);

    float c_st[4];
#pragma unroll
    for (int r = 0; r < 4; ++r) c_st[r] = 0.0f;

    // prologue: stage X[t0] into buffer 0 (drained by the barrier below)
    {
        const int t0 = dir ? (TSTEPS - 1) : 0;
        STAGE(&x_stage[0][0], t0);
    }
    __syncthreads();

    for (int st = 0; st < TSTEPS; ++st) {
        const int t = dir ? (TSTEPS - 1 - st) : st;
        if (st + 1 < TSTEPS) {
            const int t1 = dir ? (TSTEPS - 2 - st) : (st + 1);
            STAGE(&x_stage[(st + 1) & 1][0], t1);
        }
        const short* xs_cur = &x_stage[st & 1][0];

        floatx4 acc[4];
#pragma unroll
        for (int i = 0; i < 4; ++i) acc[i] = (floatx4){0.f, 0.f, 0.f, 0.f};

        // 4-buffer distance-2 register pipeline over kb. The in-loop boundary
        // (uniform condition) completes last tail's async partner-h pull:
        // vmcnt(16) retires the pull (>=26 younger VMEM ops issued since) while
        // leaving the freshest weight prefetches in flight; raw s_barrier (no
        // full drain!) publishes it; the one stale A-prefetch is re-issued.
        short8 W0[4], W1[4], Y0[4], Y1[4], a0, a1;
        LOADW(W0, 0);
        LOADW(W1, 1);
        LOADA(a0, 0);
#pragma unroll 1
        for (int kb = 0; kb < KB - 4; kb += 4) {
            LOADW(Y0, kb + 2); LOADA(a1, kb + 1); MFMA4(a0, W0);
            LOADW(Y1, kb + 3); LOADA(a0, kb + 2); MFMA4(a1, W1);
            LOADW(W0, kb + 4); LOADA(a1, kb + 3); MFMA4(a0, Y0);
            LOADW(W1, kb + 5); LOADA(a0, kb + 4); MFMA4(a1, Y1);
            if (st > 0 && kb + 4 == SP) {
                asm volatile("s_waitcnt vmcnt(16)" ::: "memory");
                __builtin_amdgcn_s_barrier();
                __builtin_amdgcn_sched_barrier(0);
                LOADA(a0, kb + 4);  // re-read: prefetch above was pre-barrier
            }
        }
        LOADW(Y0, KB - 2); LOADA(a1, KB - 3); MFMA4(a0, W0);
        LOADW(Y1, KB - 1); LOADA(a0, KB - 2); MFMA4(a1, W1);
        LOADA(a1, KB - 1); MFMA4(a0, Y0);
        MFMA4(a1, Y1);

        __syncthreads();  // (1) all h_lds / x_stage reads of this step done

        // cell update -> own h_lds columns (all 4 gates thread-local)
        {
            const int unit = half * 128 + wv * 16 + lr;
            const float bi  = bias_sh[0 * 256 + unit];
            const float bf_ = bias_sh[1 * 256 + unit];
            const float bg_ = bias_sh[2 * 256 + unit];
            const float bo_ = bias_sh[3 * 256 + unit];
#pragma unroll
            for (int r = 0; r < 4; ++r) {
                float iv = acc[0][r] + bi;
                float fv = acc[1][r] + bf_;
                float gv = acc[2][r] + bg_;
                float ov = acc[3][r] + bo_;
                float c = sigf(fv) * c_st[r] + sigf(iv) * tanhf_fast(gv);
                c_st[r] = c;
                float h = sigf(ov) * tanhf_fast(c);
                h_lds[quad * 4 + r][unit] = f2bf(h);
            }
        }
        __syncthreads();  // (2) own half complete in h_lds

        // own-half writeback: coalesced agent-scope 8B stores (partner reads)
        {
            const int row = tid >> 5, c4 = tid & 31;
            unsigned long long v = *reinterpret_cast<const unsigned long long*>(
                &h_lds[row][half * 128 + c4 * 4]);
            __hip_atomic_store(
                reinterpret_cast<unsigned long long*>(
                    Hout + ((size_t)t * BATCH + bbase + row) * OSTR +
                    dir * 256 + half * 128) + c4,
                v, __ATOMIC_RELAXED, __HIP_MEMORY_SCOPE_AGENT);
        }
        __syncthreads();  // (3) stores drained -> safe to publish

        if (st + 1 < TSTEPS) {
            if (tid == 0) {
                __hip_atomic_store(&flags[myf], st + 1, __ATOMIC_RELEASE,
                                   __HIP_MEMORY_SCOPE_AGENT);
                while (__hip_atomic_load(&flags[paf], __ATOMIC_ACQUIRE,
                                         __HIP_MEMORY_SCOPE_AGENT) <= st)
                    __builtin_amdgcn_s_sleep(1);
            }
            __syncthreads();  // (4) partner h(t) published at coherence point

            // async pull of partner half directly into h_lds colC: 2 rows per
            // wave, lanes 0..15 x 16B (row pad keeps rows disjoint). Completion
            // is enforced by next step's in-loop vmcnt(16)+s_barrier boundary.
            // Lines are cold in this CU's caches (first touch this dispatch),
            // writer stored agent-scope -> plain cached load reads fresh data.
            if (lane < 16) {
                const short* gsrc = Hout + ((size_t)t * BATCH + bbase) * OSTR +
                                    dir * 256 + colC;
                load_lds16(gsrc + (size_t)(wv * 2) * OSTR + lane * 8,
                           &h_lds[wv * 2][colC]);
                load_lds16(gsrc + (size_t)(wv * 2 + 1) * OSTR + lane * 8,
                           &h_lds[wv * 2 + 1][colC]);
            }
        }
    }
}

// ---------------- heads (fp32 output; h1 row stride 512) -------------------
__global__ __launch_bounds__(256) void lout_kernel(
    const short* __restrict__ h1, const float* __restrict__ Wlp,
    const float* __restrict__ blp, float* __restrict__ out)
{
    __shared__ float wl[6 * 512];
    for (int i = threadIdx.x; i < 6 * 512; i += 256) wl[i] = Wlp[i];
    __syncthreads();

    int idx = blockIdx.x * 256 + threadIdx.x;
    if (idx >= BATCH * 60) return;
    int b = idx & (BATCH - 1);
    int s = idx >> 10;
    const short* hrow = h1 + ((size_t)(s + 1) * BATCH + b) * 512;

    float acc[6];
#pragma unroll
    for (int j = 0; j < 6; ++j) acc[j] = blp[j];
    for (int k = 0; k < 512; k += 8) {
        short8 hv = *reinterpret_cast<const short8*>(hrow + k);
#pragma unroll
        for (int e = 0; e < 8; ++e) {
            float h = bf2f(hv[e]);
#pragma unroll
            for (int j = 0; j < 6; ++j) acc[j] += h * wl[j * 512 + k + e];
        }
    }
    float* orow = out + ((size_t)b * 60 + s) * 14;
#pragma unroll
    for (int j = 0; j < 6; ++j) orow[j] = acc[j];
}

__global__ __launch_bounds__(256) void gout_kernel(
    const short* __restrict__ h1, const float* __restrict__ Wgp,
    const float* __restrict__ bgp, float* __restrict__ out)
{
    __shared__ float wg[8 * 1024];
    for (int i = threadIdx.x; i < 8 * 1024; i += 256) wg[i] = Wgp[i];
    __syncthreads();

    int b = blockIdx.x * 256 + threadIdx.x;
    if (b >= BATCH) return;
    const short* ha = h1 + (size_t)b * 512;
    const short* hb = h1 + ((size_t)61 * BATCH + b) * 512;

    float acc[8];
#pragma unroll
    for (int j = 0; j < 8; ++j) acc[j] = bgp[j];
    for (int k = 0; k < 512; k += 8) {
        short8 h1v = *reinterpret_cast<const short8*>(ha + k);
        short8 h2v = *reinterpret_cast<const short8*>(hb + k);
#pragma unroll
        for (int e = 0; e < 8; ++e) {
            float v1 = bf2f(h1v[e]);
            float v2 = bf2f(h2v[e]);
#pragma unroll
            for (int j = 0; j < 8; ++j) {
                acc[j] += v1 * wg[j * 1024 + k + e];
                acc[j] += v2 * wg[j * 1024 + 512 + k + e];
            }
        }
    }
    for (int s = 0; s < 60; ++s) {
        float* orow = out + ((size_t)b * 60 + s) * 14 + 6;
#pragma unroll
        for (int j = 0; j < 8; ++j) orow[j] = acc[j];
    }
}

// ---------------- launch ---------------------------------------------------
extern "C" void kernel_launch(void* const* d_in, const int* in_sizes, int n_in,
                              void* d_out, int out_size, void* d_ws, size_t ws_size,
                              hipStream_t stream)
{
    const float* x    = (const float*)d_in[0];
    const float* Wg   = (const float*)d_in[1];
    const float* bg   = (const float*)d_in[2];
    const float* Wl   = (const float*)d_in[3];
    const float* bl   = (const float*)d_in[4];
    const float* Wih0 = (const float*)d_in[5];
    const float* Whh0 = (const float*)d_in[6];
    const float* bih0 = (const float*)d_in[7];
    const float* bhh0 = (const float*)d_in[8];
    const float* Wih1 = (const float*)d_in[9];
    const float* Whh1 = (const float*)d_in[10];
    const float* bih1 = (const float*)d_in[11];
    const float* bhh1 = (const float*)d_in[12];
    const float* Wgp  = (const float*)d_in[13];
    const float* bgp  = (const float*)d_in[14];
    const float* Wlp  = (const float*)d_in[15];
    const float* blp  = (const float*)d_in[16];
    float* out = (float*)d_out;

    const size_t seq_e = (size_t)TSTEPS * BATCH * 264;  // 16,760,832 (stride 264)
    const size_t h0_e  = (size_t)TSTEPS * BATCH * 520;  // 33,013,760 (stride 520)
    const size_t h1_e  = (size_t)TSTEPS * BATCH * 512;  // 32,505,856 (stride 512)
    const size_t cat_e = 8 * 24 * 8192;                 //  1,572,864 (shared, max)
    const size_t cat0_n = 8 * 16 * 8192;                //  layer0 repack count

    short* seq = (short*)d_ws;
    short* h0  = seq + seq_e;
    short* h1  = h0 + h0_e;
    short* cat = h1 + h1_e;
    int*   flags = (int*)(cat + cat_e);                 // 2 layers x 256 ints
    const size_t need = (seq_e + h0_e + h1_e + cat_e) * sizeof(short) + 2048;
    if (ws_size < need) return;

    hipMemsetAsync(flags, 0, 2 * 256 * sizeof(int), stream);

    embed_kernel<<<BATCH, 256, 0, stream>>>(x, Wg, bg, Wl, bl, seq);

    repack_kernel<<<(int)((cat0_n + 255) / 256), 256, 0, stream>>>(Wih0, Whh0, cat, 256);
    lstm_fused_kernel<512, 264, 520><<<256, 512, 0, stream>>>(seq, cat, bih0, bhh0, h0, flags);

    repack_kernel<<<(int)((cat_e + 255) / 256), 256, 0, stream>>>(Wih1, Whh1, cat, 512);
    lstm_fused_kernel<768, 520, 512><<<256, 512, 0, stream>>>(h0, cat, bih1, bhh1, h1, flags + 256);

    lout_kernel<<<(BATCH * 60 + 255) / 256, 256, 0, stream>>>(h1, Wlp, blp, out);
    gout_kernel<<<(BATCH + 255) / 256, 256, 0, stream>>>(h1, Wgp, bgp, out);
}

// Round 8
// 1068.170 us; speedup vs baseline: 3.7440x; 1.3647x over previous
//
#include <hip/hip_runtime.h>
#include <hip/hip_bf16.h>
#include <cstdint>
#include <cstddef>

// Model: B=1024, S=60, CIN=25, D=256, H=256, T=S+2=62
// Inputs fp32, output fp32; internal bf16 activations/weights, fp32 accum.
//
// Round-19 = EXACT R14 structure (best verified, 1412us) with ONE change:
// all exchange atomics are RELAXED (no acquire/release). Theory: agent-scope
// ACQUIRE on gfx950 compiles to buffer_inv (L2 invalidate; L2 is not the
// agent coherence point) -- executed per step by every one of 256 WGs, it
// thrashes the XCD-shared L2 that the weight stream depends on. Evidence:
// R13 (no exchange) ~125 GB/s/CU, zero tail; R14 (+1 acquire/step) ~68
// GB/s/CU; R17/R18 data-path changes neutral; R15 (more fencing) collapsed.
// Ordering stays correct with RELAXED: producer h-stores are drained to the
// coherence point by __syncthreads (vmcnt0) BEFORE the flag post, and
// consumer data loads issue only after the poll load retires (branch dep),
// all at the same coherence point -> data-before-flag / flag-before-data.
// Session rules: weights NEVER via LDS (R12/R16); exchange timing stays
// loose (R15); one change per round.

typedef __attribute__((ext_vector_type(8))) short short8;
typedef __attribute__((ext_vector_type(4))) float floatx4;

#define BATCH 1024
#define TSTEPS 62

__device__ __forceinline__ float bf2f(short s) {
    union { unsigned u; float f; } v;
    v.u = ((unsigned)(unsigned short)s) << 16;
    return v.f;
}
__device__ __forceinline__ short f2bf(float f) {
    union { float f; unsigned u; } v; v.f = f;
    unsigned r = (v.u + 0x7fffu + ((v.u >> 16) & 1u)) >> 16;  // RNE
    return (short)r;
}
__device__ __forceinline__ float sigf(float x) {
    return __builtin_amdgcn_rcpf(1.0f + __expf(-x));
}
__device__ __forceinline__ float tanhf_fast(float x) {
    return 2.0f * __builtin_amdgcn_rcpf(1.0f + __expf(-2.0f * x)) - 1.0f;
}

// async 16B/lane global->LDS (LDS dest = uniform base + lane*16)
__device__ __forceinline__ void load_lds16(const short* g, short* l) {
    __builtin_amdgcn_global_load_lds(
        (const __attribute__((address_space(1))) void*)g,
        (__attribute__((address_space(3))) void*)l, 16, 0, 0);
}

// ------------- repack [Wih|Whh] into unit-split wave-blocked layout --------
// dst idx = ((((dh*8 + w)*KB + kb)*4 + g)*64 + lane)*8 + j
//   dh = dir*2 + half
//   row = g*256 + half*128 + w*16 + (lane&15)
//   k   = kb*32 + (lane>>4)*8 + j
__global__ __launch_bounds__(256) void repack_kernel(
    const float* __restrict__ Wih, const float* __restrict__ Whh,
    short* __restrict__ Wp, int XI)
{
    const int KB = (XI + 256) / 32;
    int idx = blockIdx.x * 256 + threadIdx.x;
    if (idx >= 8 * KB * 8192) return;
    int j    = idx & 7;
    int lane = (idx >> 3) & 63;
    int g    = (idx >> 9) & 3;
    int rem  = idx >> 11;
    int kb   = rem % KB;
    int rem2 = rem / KB;
    int w    = rem2 & 7;
    int dh   = rem2 >> 3;       // 0..3
    int dir  = dh >> 1;
    int half = dh & 1;
    int row  = g * 256 + half * 128 + w * 16 + (lane & 15);
    int k    = kb * 32 + (lane >> 4) * 8 + j;
    float v = (k < XI) ? Wih[((size_t)dir * 1024 + row) * XI + k]
                       : Whh[((size_t)dir * 1024 + row) * 256 + (k - XI)];
    Wp[idx] = f2bf(v);
}

// ---------------- embed: seq[t][b][d], row stride 264 ----------------------
__global__ __launch_bounds__(256) void embed_kernel(
    const float* __restrict__ x, const float* __restrict__ Wg,
    const float* __restrict__ bg, const float* __restrict__ Wl,
    const float* __restrict__ bl, short* __restrict__ seq)
{
    const int b = blockIdx.x;
    const int d = threadIdx.x;  // 256 = D
    __shared__ float xs[1500];
    for (int i = d; i < 1500; i += 256) xs[i] = x[(size_t)b * 1500 + i];
    __syncthreads();

    float g = bg[d];
#pragma unroll
    for (int c = 0; c < 16; ++c) g += xs[9 + c] * Wg[d * 16 + c];
    short gb = f2bf(g);
    seq[((size_t)0 * BATCH + b) * 264 + d] = gb;
    seq[((size_t)61 * BATCH + b) * 264 + d] = gb;

    for (int t = 0; t < 60; ++t) {
        float v = bl[d];
#pragma unroll
        for (int c = 0; c < 9; ++c) v += xs[t * 25 + c] * Wl[d * 9 + c];
        seq[((size_t)(t + 1) * BATCH + b) * 264 + d] = f2bf(v);
    }
}

// ---------------- persistent biLSTM layer (unit-split, 256 WGs) ------------
#define LOADW(BUF, kbq)                                                          \
    {                                                                            \
        _Pragma("unroll")                                                        \
        for (int g = 0; g < 4; ++g)                                              \
            BUF[g] = *reinterpret_cast<const short8*>(                           \
                wpb + (size_t)(kbq) * 2048 + g * 512);                           \
    }
#define LOADA(DST, kbg)                                                          \
    {                                                                            \
        DST = ((kbg) < XB)                                                       \
            ? *reinterpret_cast<const short8*>(xs_cur + lr * (XI + 8) + (kbg) * 32 + quad * 8) \
            : *reinterpret_cast<const short8*>(&h_lds[lr][((kbg) - XB) * 32 + quad * 8]); \
    }
#define MFMA4(AV, BUF)                                                           \
    {                                                                            \
        _Pragma("unroll")                                                        \
        for (int g = 0; g < 4; ++g)                                              \
            acc[g] = __builtin_amdgcn_mfma_f32_16x16x32_bf16(                    \
                AV, BUF[g], acc[g], 0, 0, 0);                                    \
    }
// stage one 16-row X tile (XI cols of XSTR-stride rows): 8 waves x 2 rows
#define STAGE(BUFP, T1)                                                          \
    {                                                                            \
        const short* xtb = X + ((size_t)(T1) * BATCH + bbase) * XSTR;            \
        _Pragma("unroll")                                                        \
        for (int i = 0; i < 2; ++i) {                                            \
            int row = wv * 2 + i;                                                \
            if (XI == 512 || lane < 32)                                          \
                load_lds16(xtb + (size_t)row * XSTR + lane * 8,                  \
                           (BUFP) + row * (XI + 8));                             \
        }                                                                        \
    }

template <int KK, int XSTR, int OSTR>  // KK=512: XI=256 (layer0); KK=768: XI=512
__global__ __launch_bounds__(512, 2) void lstm_fused_kernel(
    const short* __restrict__ X,      // (62,1024,XSTR) bf16, first XI cols used
    const short* __restrict__ Wcat,   // unit-split wave-blocked [Wih|Whh]
    const float* __restrict__ bih, const float* __restrict__ bhh,
    short* __restrict__ Hout,         // (62,1024,OSTR); dir d -> cols [256d,..)
    int* __restrict__ flags)          // 128 pairs x 2 halves, zeroed pre-launch
{
    constexpr int XI = KK - 256;
    constexpr int KB = KK / 32;   // 16 or 24 (divisible by 4)
    constexpr int XB = XI / 32;

    const int wg    = blockIdx.x;     // 256 = (2 halves) x (2 dirs x 64 tiles)
    const int half  = wg >> 7;
    const int pair  = wg & 127;       // dir*64 + tile
    const int dir   = pair >> 6;
    const int bbase = (pair & 63) * 16;
    const int tid   = threadIdx.x;
    const int wv    = tid >> 6;       // 0..7
    const int lane  = tid & 63;
    const int quad  = lane >> 4;
    const int lr    = lane & 15;

    __shared__ __align__(16) short h_lds[16][264];
    __shared__ __align__(16) short x_stage[2][16 * (XI + 8)];
    __shared__ float bias_sh[1024];
    for (int i = tid; i < 16 * 264; i += 512) (&h_lds[0][0])[i] = 0;
    for (int i = tid; i < 1024; i += 512)
        bias_sh[i] = bih[dir * 1024 + i] + bhh[dir * 1024 + i];

    // per-wave weight stream: KB blocks of 2048 shorts (4 gates x 512)
    const short* wpb = Wcat +
        ((size_t)((dir * 2 + half) * 8 + wv) * KB) * 2048 + lane * 8;

    const int colC = (half ^ 1) * 128;
    const int myf = (pair << 1) | half;
    const int paf = (pair << 1) | (half ^ 1);

    float c_st[4];
#pragma unroll
    for (int r = 0; r < 4; ++r) c_st[r] = 0.0f;

    // prologue: stage X[t0] into buffer 0 (drained by the barrier below)
    {
        const int t0 = dir ? (TSTEPS - 1) : 0;
        STAGE(&x_stage[0][0], t0);
    }
    __syncthreads();

    for (int st = 0; st < TSTEPS; ++st) {
        const int t = dir ? (TSTEPS - 1 - st) : st;
        if (st + 1 < TSTEPS) {
            const int t1 = dir ? (TSTEPS - 2 - st) : (st + 1);
            STAGE(&x_stage[(st + 1) & 1][0], t1);
        }
        const short* xs_cur = &x_stage[st & 1][0];

        floatx4 acc[4];
#pragma unroll
        for (int i = 0; i < 4; ++i) acc[i] = (floatx4){0.f, 0.f, 0.f, 0.f};

        // 4-buffer distance-2 register pipeline over kb
        short8 W0[4], W1[4], Y0[4], Y1[4], a0, a1;
        LOADW(W0, 0);
        LOADW(W1, 1);
        LOADA(a0, 0);
#pragma unroll 1
        for (int kb = 0; kb < KB - 4; kb += 4) {
            LOADW(Y0, kb + 2); LOADA(a1, kb + 1); MFMA4(a0, W0);
            LOADW(Y1, kb + 3); LOADA(a0, kb + 2); MFMA4(a1, W1);
            LOADW(W0, kb + 4); LOADA(a1, kb + 3); MFMA4(a0, Y0);
            LOADW(W1, kb + 5); LOADA(a0, kb + 4); MFMA4(a1, Y1);
        }
        LOADW(Y0, KB - 2); LOADA(a1, KB - 3); MFMA4(a0, W0);
        LOADW(Y1, KB - 1); LOADA(a0, KB - 2); MFMA4(a1, W1);
        LOADA(a1, KB - 1); MFMA4(a0, Y0);
        MFMA4(a1, Y1);

        __syncthreads();  // (1) all h_lds / x_stage reads of this step done

        // cell update -> own h_lds columns (all 4 gates thread-local)
        {
            const int unit = half * 128 + wv * 16 + lr;
            const float bi  = bias_sh[0 * 256 + unit];
            const float bf_ = bias_sh[1 * 256 + unit];
            const float bg_ = bias_sh[2 * 256 + unit];
            const float bo_ = bias_sh[3 * 256 + unit];
#pragma unroll
            for (int r = 0; r < 4; ++r) {
                float iv = acc[0][r] + bi;
                float fv = acc[1][r] + bf_;
                float gv = acc[2][r] + bg_;
                float ov = acc[3][r] + bo_;
                float c = sigf(fv) * c_st[r] + sigf(iv) * tanhf_fast(gv);
                c_st[r] = c;
                float h = sigf(ov) * tanhf_fast(c);
                h_lds[quad * 4 + r][unit] = f2bf(h);
            }
        }
        __syncthreads();  // (2) own half complete in h_lds

        // own-half writeback: coalesced agent-scope 8B stores (partner reads)
        {
            const int row = tid >> 5, c4 = tid & 31;
            unsigned long long v = *reinterpret_cast<const unsigned long long*>(
                &h_lds[row][half * 128 + c4 * 4]);
            __hip_atomic_store(
                reinterpret_cast<unsigned long long*>(
                    Hout + ((size_t)t * BATCH + bbase + row) * OSTR +
                    dir * 256 + half * 128) + c4,
                v, __ATOMIC_RELAXED, __HIP_MEMORY_SCOPE_AGENT);
        }
        __syncthreads();  // (3) stores drained (vmcnt 0 at coherence point)
                          //     -> flag may be posted RELAXED

        if (st + 1 < TSTEPS) {
            if (tid == 0) {
                __hip_atomic_store(&flags[myf], st + 1, __ATOMIC_RELAXED,
                                   __HIP_MEMORY_SCOPE_AGENT);
                while (__hip_atomic_load(&flags[paf], __ATOMIC_RELAXED,
                                         __HIP_MEMORY_SCOPE_AGENT) <= st)
                    __builtin_amdgcn_s_sleep(1);
            }
            __syncthreads();  // (4) partner h(t) at coherence point; no L2
                              //     invalidate needed: pull loads below are
                              //     agent-scope (bypass stale caches) and
                              //     issue only after the poll load retired

            // pull partner half into h_lds
            {
                const int row = tid >> 5, c4 = tid & 31;
                unsigned long long v = __hip_atomic_load(
                    reinterpret_cast<const unsigned long long*>(
                        Hout + ((size_t)t * BATCH + bbase + row) * OSTR +
                        dir * 256 + colC) + c4,
                    __ATOMIC_RELAXED, __HIP_MEMORY_SCOPE_AGENT);
                *reinterpret_cast<unsigned long long*>(
                    &h_lds[row][colC + c4 * 4]) = v;
            }
            __syncthreads();  // (5) h_lds complete for next step
        }
    }
}

// ---------------- heads (fp32 output; h1 row stride 512) -------------------
__global__ __launch_bounds__(256) void lout_kernel(
    const short* __restrict__ h1, const float* __restrict__ Wlp,
    const float* __restrict__ blp, float* __restrict__ out)
{
    __shared__ float wl[6 * 512];
    for (int i = threadIdx.x; i < 6 * 512; i += 256) wl[i] = Wlp[i];
    __syncthreads();

    int idx = blockIdx.x * 256 + threadIdx.x;
    if (idx >= BATCH * 60) return;
    int b = idx & (BATCH - 1);
    int s = idx >> 10;
    const short* hrow = h1 + ((size_t)(s + 1) * BATCH + b) * 512;

    float acc[6];
#pragma unroll
    for (int j = 0; j < 6; ++j) acc[j] = blp[j];
    for (int k = 0; k < 512; k += 8) {
        short8 hv = *reinterpret_cast<const short8*>(hrow + k);
#pragma unroll
        for (int e = 0; e < 8; ++e) {
            float h = bf2f(hv[e]);
#pragma unroll
            for (int j = 0; j < 6; ++j) acc[j] += h * wl[j * 512 + k + e];
        }
    }
    float* orow = out + ((size_t)b * 60 + s) * 14;
#pragma unroll
    for (int j = 0; j < 6; ++j) orow[j] = acc[j];
}

__global__ __launch_bounds__(256) void gout_kernel(
    const short* __restrict__ h1, const float* __restrict__ Wgp,
    const float* __restrict__ bgp, float* __restrict__ out)
{
    __shared__ float wg[8 * 1024];
    for (int i = threadIdx.x; i < 8 * 1024; i += 256) wg[i] = Wgp[i];
    __syncthreads();

    int b = blockIdx.x * 256 + threadIdx.x;
    if (b >= BATCH) return;
    const short* ha = h1 + (size_t)b * 512;
    const short* hb = h1 + ((size_t)61 * BATCH + b) * 512;

    float acc[8];
#pragma unroll
    for (int j = 0; j < 8; ++j) acc[j] = bgp[j];
    for (int k = 0; k < 512; k += 8) {
        short8 h1v = *reinterpret_cast<const short8*>(ha + k);
        short8 h2v = *reinterpret_cast<const short8*>(hb + k);
#pragma unroll
        for (int e = 0; e < 8; ++e) {
            float v1 = bf2f(h1v[e]);
            float v2 = bf2f(h2v[e]);
#pragma unroll
            for (int j = 0; j < 8; ++j) {
                acc[j] += v1 * wg[j * 1024 + k + e];
                acc[j] += v2 * wg[j * 1024 + 512 + k + e];
            }
        }
    }
    for (int s = 0; s < 60; ++s) {
        float* orow = out + ((size_t)b * 60 + s) * 14 + 6;
#pragma unroll
        for (int j = 0; j < 8; ++j) orow[j] = acc[j];
    }
}

// ---------------- launch ---------------------------------------------------
extern "C" void kernel_launch(void* const* d_in, const int* in_sizes, int n_in,
                              void* d_out, int out_size, void* d_ws, size_t ws_size,
                              hipStream_t stream)
{
    const float* x    = (const float*)d_in[0];
    const float* Wg   = (const float*)d_in[1];
    const float* bg   = (const float*)d_in[2];
    const float* Wl   = (const float*)d_in[3];
    const float* bl   = (const float*)d_in[4];
    const float* Wih0 = (const float*)d_in[5];
    const float* Whh0 = (const float*)d_in[6];
    const float* bih0 = (const float*)d_in[7];
    const float* bhh0 = (const float*)d_in[8];
    const float* Wih1 = (const float*)d_in[9];
    const float* Whh1 = (const float*)d_in[10];
    const float* bih1 = (const float*)d_in[11];
    const float* bhh1 = (const float*)d_in[12];
    const float* Wgp  = (const float*)d_in[13];
    const float* bgp  = (const float*)d_in[14];
    const float* Wlp  = (const float*)d_in[15];
    const float* blp  = (const float*)d_in[16];
    float* out = (float*)d_out;

    const size_t seq_e = (size_t)TSTEPS * BATCH * 264;  // 16,760,832 (stride 264)
    const size_t h0_e  = (size_t)TSTEPS * BATCH * 520;  // 33,013,760 (stride 520)
    const size_t h1_e  = (size_t)TSTEPS * BATCH * 512;  // 32,505,856 (stride 512)
    const size_t cat_e = 8 * 24 * 8192;                 //  1,572,864 (shared, max)
    const size_t cat0_n = 8 * 16 * 8192;                //  layer0 repack count

    short* seq = (short*)d_ws;
    short* h0  = seq + seq_e;
    short* h1  = h0 + h0_e;
    short* cat = h1 + h1_e;
    int*   flags = (int*)(cat + cat_e);                 // 2 layers x 256 ints
    const size_t need = (seq_e + h0_e + h1_e + cat_e) * sizeof(short) + 2048;
    if (ws_size < need) return;

    hipMemsetAsync(flags, 0, 2 * 256 * sizeof(int), stream);

    embed_kernel<<<BATCH, 256, 0, stream>>>(x, Wg, bg, Wl, bl, seq);

    repack_kernel<<<(int)((cat0_n + 255) / 256), 256, 0, stream>>>(Wih0, Whh0, cat, 256);
    lstm_fused_kernel<512, 264, 520><<<256, 512, 0, stream>>>(seq, cat, bih0, bhh0, h0, flags);

    repack_kernel<<<(int)((cat_e + 255) / 256), 256, 0, stream>>>(Wih1, Whh1, cat, 512);
    lstm_fused_kernel<768, 520, 512><<<256, 512, 0, stream>>>(h0, cat, bih1, bhh1, h1, flags + 256);

    lout_kernel<<<(BATCH * 60 + 255) / 256, 256, 0, stream>>>(h1, Wlp, blp, out);
    gout_kernel<<<(BATCH + 255) / 256, 256, 0, stream>>>(h1, Wgp, bgp, out);
}

// Round 10
// 970.159 us; speedup vs baseline: 4.1223x; 1.1010x over previous
//
#include <hip/hip_runtime.h>
#include <hip/hip_bf16.h>
#include <cstdint>
#include <cstddef>

// Model: B=1024, S=60, CIN=25, D=256, H=256, T=S+2=62
// Inputs fp32, output fp32; internal bf16 activations/weights, fp32 accum.
//
// Round-21 = R19 (1068us verified) + register-resident Whh at HALF dose:
// 4 resident blocks (KB-4..KB-1, 64 VGPR) instead of R20's 8 (128 VGPR).
// R20 failed correctness (absmax 3.5e-3; replay-phase 468) despite formally
// identical accumulation order -- prime suspect is the 256-VGPR cap forced
// by launch_bounds(512,2): ~216+ demand sat on the allocator cliff (spill
// of short8 across barriers + divergent poll). 4 blocks keeps demand ~152.
// Diagnostic: pass with absmax EXACTLY 0.0004882812 -> order-safe, bank the
// byte cut (L1 786->655 KB/step, L0 524->393); fail -> resident concept has
// a hidden mechanism, revert to R19 and stop.
// Session rules: weights NEVER via LDS (R12/R16); exchange loose (R15);
// RELAXED handshake only (R19); one change per round.

typedef __attribute__((ext_vector_type(8))) short short8;
typedef __attribute__((ext_vector_type(4))) float floatx4;

#define BATCH 1024
#define TSTEPS 62

__device__ __forceinline__ float bf2f(short s) {
    union { unsigned u; float f; } v;
    v.u = ((unsigned)(unsigned short)s) << 16;
    return v.f;
}
__device__ __forceinline__ short f2bf(float f) {
    union { float f; unsigned u; } v; v.f = f;
    unsigned r = (v.u + 0x7fffu + ((v.u >> 16) & 1u)) >> 16;  // RNE
    return (short)r;
}
__device__ __forceinline__ float sigf(float x) {
    return __builtin_amdgcn_rcpf(1.0f + __expf(-x));
}
__device__ __forceinline__ float tanhf_fast(float x) {
    return 2.0f * __builtin_amdgcn_rcpf(1.0f + __expf(-2.0f * x)) - 1.0f;
}

// async 16B/lane global->LDS (LDS dest = uniform base + lane*16)
__device__ __forceinline__ void load_lds16(const short* g, short* l) {
    __builtin_amdgcn_global_load_lds(
        (const __attribute__((address_space(1))) void*)g,
        (__attribute__((address_space(3))) void*)l, 16, 0, 0);
}

// ------------- repack [Wih|Whh] into unit-split wave-blocked layout --------
// dst idx = ((((dh*8 + w)*KB + kb)*4 + g)*64 + lane)*8 + j
//   dh = dir*2 + half
//   row = g*256 + half*128 + w*16 + (lane&15)
//   k   = kb*32 + (lane>>4)*8 + j
__global__ __launch_bounds__(256) void repack_kernel(
    const float* __restrict__ Wih, const float* __restrict__ Whh,
    short* __restrict__ Wp, int XI)
{
    const int KB = (XI + 256) / 32;
    int idx = blockIdx.x * 256 + threadIdx.x;
    if (idx >= 8 * KB * 8192) return;
    int j    = idx & 7;
    int lane = (idx >> 3) & 63;
    int g    = (idx >> 9) & 3;
    int rem  = idx >> 11;
    int kb   = rem % KB;
    int rem2 = rem / KB;
    int w    = rem2 & 7;
    int dh   = rem2 >> 3;       // 0..3
    int dir  = dh >> 1;
    int half = dh & 1;
    int row  = g * 256 + half * 128 + w * 16 + (lane & 15);
    int k    = kb * 32 + (lane >> 4) * 8 + j;
    float v = (k < XI) ? Wih[((size_t)dir * 1024 + row) * XI + k]
                       : Whh[((size_t)dir * 1024 + row) * 256 + (k - XI)];
    Wp[idx] = f2bf(v);
}

// ---------------- embed: seq[t][b][d], row stride 264 ----------------------
__global__ __launch_bounds__(256) void embed_kernel(
    const float* __restrict__ x, const float* __restrict__ Wg,
    const float* __restrict__ bg, const float* __restrict__ Wl,
    const float* __restrict__ bl, short* __restrict__ seq)
{
    const int b = blockIdx.x;
    const int d = threadIdx.x;  // 256 = D
    __shared__ float xs[1500];
    for (int i = d; i < 1500; i += 256) xs[i] = x[(size_t)b * 1500 + i];
    __syncthreads();

    float g = bg[d];
#pragma unroll
    for (int c = 0; c < 16; ++c) g += xs[9 + c] * Wg[d * 16 + c];
    short gb = f2bf(g);
    seq[((size_t)0 * BATCH + b) * 264 + d] = gb;
    seq[((size_t)61 * BATCH + b) * 264 + d] = gb;

    for (int t = 0; t < 60; ++t) {
        float v = bl[d];
#pragma unroll
        for (int c = 0; c < 9; ++c) v += xs[t * 25 + c] * Wl[d * 9 + c];
        seq[((size_t)(t + 1) * BATCH + b) * 264 + d] = f2bf(v);
    }
}

// ---------------- persistent biLSTM layer (unit-split, 256 WGs) ------------
#define LOADW(BUF, kbq)                                                          \
    {                                                                            \
        _Pragma("unroll")                                                        \
        for (int g = 0; g < 4; ++g)                                              \
            BUF[g] = *reinterpret_cast<const short8*>(                           \
                wpb + (size_t)(kbq) * 2048 + g * 512);                           \
    }
#define LOADA(DST, kbg)                                                          \
    {                                                                            \
        DST = ((kbg) < XB)                                                       \
            ? *reinterpret_cast<const short8*>(xs_cur + lr * (XI + 8) + (kbg) * 32 + quad * 8) \
            : *reinterpret_cast<const short8*>(&h_lds[lr][((kbg) - XB) * 32 + quad * 8]); \
    }
#define MFMA4(AV, BUF)                                                           \
    {                                                                            \
        _Pragma("unroll")                                                        \
        for (int g = 0; g < 4; ++g)                                              \
            acc[g] = __builtin_amdgcn_mfma_f32_16x16x32_bf16(                    \
                AV, BUF[g], acc[g], 0, 0, 0);                                    \
    }
#define MFMA4R(AV, i)                                                            \
    {                                                                            \
        _Pragma("unroll")                                                        \
        for (int g = 0; g < 4; ++g)                                              \
            acc[g] = __builtin_amdgcn_mfma_f32_16x16x32_bf16(                    \
                AV, RW[i][g], acc[g], 0, 0, 0);                                  \
    }
// stage one 16-row X tile (XI cols of XSTR-stride rows): 8 waves x 2 rows
#define STAGE(BUFP, T1)                                                          \
    {                                                                            \
        const short* xtb = X + ((size_t)(T1) * BATCH + bbase) * XSTR;            \
        _Pragma("unroll")                                                        \
        for (int i = 0; i < 2; ++i) {                                            \
            int row = wv * 2 + i;                                                \
            if (XI == 512 || lane < 32)                                          \
                load_lds16(xtb + (size_t)row * XSTR + lane * 8,                  \
                           (BUFP) + row * (XI + 8));                             \
        }                                                                        \
    }

template <int KK, int XSTR, int OSTR>  // KK=512: XI=256 (layer0); KK=768: XI=512
__global__ __launch_bounds__(512, 2) void lstm_fused_kernel(
    const short* __restrict__ X,      // (62,1024,XSTR) bf16, first XI cols used
    const short* __restrict__ Wcat,   // unit-split wave-blocked [Wih|Whh]
    const float* __restrict__ bih, const float* __restrict__ bhh,
    short* __restrict__ Hout,         // (62,1024,OSTR); dir d -> cols [256d,..)
    int* __restrict__ flags)          // 128 pairs x 2 halves, zeroed pre-launch
{
    constexpr int XI = KK - 256;
    constexpr int KB = KK / 32;   // 16 or 24
    constexpr int XB = XI / 32;   // 8 or 16
    constexpr int S  = KB - 4;    // streamed blocks 0..S-1; resident S..KB-1

    const int wg    = blockIdx.x;     // 256 = (2 halves) x (2 dirs x 64 tiles)
    const int half  = wg >> 7;
    const int pair  = wg & 127;       // dir*64 + tile
    const int dir   = pair >> 6;
    const int bbase = (pair & 63) * 16;
    const int tid   = threadIdx.x;
    const int wv    = tid >> 6;       // 0..7
    const int lane  = tid & 63;
    const int quad  = lane >> 4;
    const int lr    = lane & 15;

    __shared__ __align__(16) short h_lds[16][264];
    __shared__ __align__(16) short x_stage[2][16 * (XI + 8)];
    __shared__ float bias_sh[1024];
    for (int i = tid; i < 16 * 264; i += 512) (&h_lds[0][0])[i] = 0;
    for (int i = tid; i < 1024; i += 512)
        bias_sh[i] = bih[dir * 1024 + i] + bhh[dir * 1024 + i];

    // per-wave weight stream: KB blocks of 2048 shorts (4 gates x 512)
    const short* wpb = Wcat +
        ((size_t)((dir * 2 + half) * 8 + wv) * KB) * 2048 + lane * 8;

    // register-resident Whh tail: blocks KB-4..KB-1, loaded once (64 VGPR)
    short8 RW[4][4];
#pragma unroll
    for (int i = 0; i < 4; ++i)
#pragma unroll
        for (int g = 0; g < 4; ++g)
            RW[i][g] = *reinterpret_cast<const short8*>(
                wpb + (size_t)(S + i) * 2048 + g * 512);

    const int colC = (half ^ 1) * 128;
    const int myf = (pair << 1) | half;
    const int paf = (pair << 1) | (half ^ 1);

    float c_st[4];
#pragma unroll
    for (int r = 0; r < 4; ++r) c_st[r] = 0.0f;

    // prologue: stage X[t0] into buffer 0 (drained by the barrier below)
    {
        const int t0 = dir ? (TSTEPS - 1) : 0;
        STAGE(&x_stage[0][0], t0);
    }
    __syncthreads();

    for (int st = 0; st < TSTEPS; ++st) {
        const int t = dir ? (TSTEPS - 1 - st) : st;
        if (st + 1 < TSTEPS) {
            const int t1 = dir ? (TSTEPS - 2 - st) : (st + 1);
            STAGE(&x_stage[(st + 1) & 1][0], t1);
        }
        const short* xs_cur = &x_stage[st & 1][0];

        floatx4 acc[4];
#pragma unroll
        for (int i = 0; i < 4; ++i) acc[i] = (floatx4){0.f, 0.f, 0.f, 0.f};

        // streamed part (blocks 0..S-1), dist-2 register pipeline
        short8 W0[4], W1[4], Y0[4], Y1[4], a0, a1;
        LOADW(W0, 0);
        LOADW(W1, 1);
        LOADA(a0, 0);
#pragma unroll 1
        for (int kb = 0; kb < S - 4; kb += 4) {
            LOADW(Y0, kb + 2); LOADA(a1, kb + 1); MFMA4(a0, W0);
            LOADW(Y1, kb + 3); LOADA(a0, kb + 2); MFMA4(a1, W1);
            LOADW(W0, kb + 4); LOADA(a1, kb + 3); MFMA4(a0, Y0);
            LOADW(W1, kb + 5); LOADA(a0, kb + 4); MFMA4(a1, Y1);
        }
        LOADW(Y0, S - 2); LOADA(a1, S - 3); MFMA4(a0, W0);
        LOADW(Y1, S - 1); LOADA(a0, S - 2); MFMA4(a1, W1);
        LOADA(a1, S - 1); MFMA4(a0, Y0);
        MFMA4(a1, Y1);

        // resident tail (blocks S..KB-1): zero weight loads
        LOADA(a0, S + 0);
        LOADA(a1, S + 1); MFMA4R(a0, 0);
        LOADA(a0, S + 2); MFMA4R(a1, 1);
        LOADA(a1, S + 3); MFMA4R(a0, 2);
        MFMA4R(a1, 3);

        __syncthreads();  // (1) all h_lds / x_stage reads of this step done

        // cell update -> own h_lds columns (all 4 gates thread-local)
        {
            const int unit = half * 128 + wv * 16 + lr;
            const float bi  = bias_sh[0 * 256 + unit];
            const float bf_ = bias_sh[1 * 256 + unit];
            const float bg_ = bias_sh[2 * 256 + unit];
            const float bo_ = bias_sh[3 * 256 + unit];
#pragma unroll
            for (int r = 0; r < 4; ++r) {
                float iv = acc[0][r] + bi;
                float fv = acc[1][r] + bf_;
                float gv = acc[2][r] + bg_;
                float ov = acc[3][r] + bo_;
                float c = sigf(fv) * c_st[r] + sigf(iv) * tanhf_fast(gv);
                c_st[r] = c;
                float h = sigf(ov) * tanhf_fast(c);
                h_lds[quad * 4 + r][unit] = f2bf(h);
            }
        }
        __syncthreads();  // (2) own half complete in h_lds

        // own-half writeback: coalesced agent-scope 8B stores (partner reads)
        {
            const int row = tid >> 5, c4 = tid & 31;
            unsigned long long v = *reinterpret_cast<const unsigned long long*>(
                &h_lds[row][half * 128 + c4 * 4]);
            __hip_atomic_store(
                reinterpret_cast<unsigned long long*>(
                    Hout + ((size_t)t * BATCH + bbase + row) * OSTR +
                    dir * 256 + half * 128) + c4,
                v, __ATOMIC_RELAXED, __HIP_MEMORY_SCOPE_AGENT);
        }
        __syncthreads();  // (3) stores drained (vmcnt 0 at coherence point)
                          //     -> flag may be posted RELAXED

        if (st + 1 < TSTEPS) {
            if (tid == 0) {
                __hip_atomic_store(&flags[myf], st + 1, __ATOMIC_RELAXED,
                                   __HIP_MEMORY_SCOPE_AGENT);
                while (__hip_atomic_load(&flags[paf], __ATOMIC_RELAXED,
                                         __HIP_MEMORY_SCOPE_AGENT) <= st)
                    __builtin_amdgcn_s_sleep(1);
            }
            __syncthreads();  // (4) partner h(t) at coherence point

            // pull partner half into h_lds
            {
                const int row = tid >> 5, c4 = tid & 31;
                unsigned long long v = __hip_atomic_load(
                    reinterpret_cast<const unsigned long long*>(
                        Hout + ((size_t)t * BATCH + bbase + row) * OSTR +
                        dir * 256 + colC) + c4,
                    __ATOMIC_RELAXED, __HIP_MEMORY_SCOPE_AGENT);
                *reinterpret_cast<unsigned long long*>(
                    &h_lds[row][colC + c4 * 4]) = v;
            }
            __syncthreads();  // (5) h_lds complete for next step
        }
    }
}

// ---------------- heads (fp32 output; h1 row stride 512) -------------------
__global__ __launch_bounds__(256) void lout_kernel(
    const short* __restrict__ h1, const float* __restrict__ Wlp,
    const float* __restrict__ blp, float* __restrict__ out)
{
    __shared__ float wl[6 * 512];
    for (int i = threadIdx.x; i < 6 * 512; i += 256) wl[i] = Wlp[i];
    __syncthreads();

    int idx = blockIdx.x * 256 + threadIdx.x;
    if (idx >= BATCH * 60) return;
    int b = idx & (BATCH - 1);
    int s = idx >> 10;
    const short* hrow = h1 + ((size_t)(s + 1) * BATCH + b) * 512;

    float acc[6];
#pragma unroll
    for (int j = 0; j < 6; ++j) acc[j] = blp[j];
    for (int k = 0; k < 512; k += 8) {
        short8 hv = *reinterpret_cast<const short8*>(hrow + k);
#pragma unroll
        for (int e = 0; e < 8; ++e) {
            float h = bf2f(hv[e]);
#pragma unroll
            for (int j = 0; j < 6; ++j) acc[j] += h * wl[j * 512 + k + e];
        }
    }
    float* orow = out + ((size_t)b * 60 + s) * 14;
#pragma unroll
    for (int j = 0; j < 6; ++j) orow[j] = acc[j];
}

__global__ __launch_bounds__(256) void gout_kernel(
    const short* __restrict__ h1, const float* __restrict__ Wgp,
    const float* __restrict__ bgp, float* __restrict__ out)
{
    __shared__ float wg[8 * 1024];
    for (int i = threadIdx.x; i < 8 * 1024; i += 256) wg[i] = Wgp[i];
    __syncthreads();

    int b = blockIdx.x * 256 + threadIdx.x;
    if (b >= BATCH) return;
    const short* ha = h1 + (size_t)b * 512;
    const short* hb = h1 + ((size_t)61 * BATCH + b) * 512;

    float acc[8];
#pragma unroll
    for (int j = 0; j < 8; ++j) acc[j] = bgp[j];
    for (int k = 0; k < 512; k += 8) {
        short8 h1v = *reinterpret_cast<const short8*>(ha + k);
        short8 h2v = *reinterpret_cast<const short8*>(hb + k);
#pragma unroll
        for (int e = 0; e < 8; ++e) {
            float v1 = bf2f(h1v[e]);
            float v2 = bf2f(h2v[e]);
#pragma unroll
            for (int j = 0; j < 8; ++j) {
                acc[j] += v1 * wg[j * 1024 + k + e];
                acc[j] += v2 * wg[j * 1024 + 512 + k + e];
            }
        }
    }
    for (int s = 0; s < 60; ++s) {
        float* orow = out + ((size_t)b * 60 + s) * 14 + 6;
#pragma unroll
        for (int j = 0; j < 8; ++j) orow[j] = acc[j];
    }
}

// ---------------- launch ---------------------------------------------------
extern "C" void kernel_launch(void* const* d_in, const int* in_sizes, int n_in,
                              void* d_out, int out_size, void* d_ws, size_t ws_size,
                              hipStream_t stream)
{
    const float* x    = (const float*)d_in[0];
    const float* Wg   = (const float*)d_in[1];
    const float* bg   = (const float*)d_in[2];
    const float* Wl   = (const float*)d_in[3];
    const float* bl   = (const float*)d_in[4];
    const float* Wih0 = (const float*)d_in[5];
    const float* Whh0 = (const float*)d_in[6];
    const float* bih0 = (const float*)d_in[7];
    const float* bhh0 = (const float*)d_in[8];
    const float* Wih1 = (const float*)d_in[9];
    const float* Whh1 = (const float*)d_in[10];
    const float* bih1 = (const float*)d_in[11];
    const float* bhh1 = (const float*)d_in[12];
    const float* Wgp  = (const float*)d_in[13];
    const float* bgp  = (const float*)d_in[14];
    const float* Wlp  = (const float*)d_in[15];
    const float* blp  = (const float*)d_in[16];
    float* out = (float*)d_out;

    const size_t seq_e = (size_t)TSTEPS * BATCH * 264;  // 16,760,832 (stride 264)
    const size_t h0_e  = (size_t)TSTEPS * BATCH * 520;  // 33,013,760 (stride 520)
    const size_t h1_e  = (size_t)TSTEPS * BATCH * 512;  // 32,505,856 (stride 512)
    const size_t cat_e = 8 * 24 * 8192;                 //  1,572,864 (shared, max)
    const size_t cat0_n = 8 * 16 * 8192;                //  layer0 repack count

    short* seq = (short*)d_ws;
    short* h0  = seq + seq_e;
    short* h1  = h0 + h0_e;
    short* cat = h1 + h1_e;
    int*   flags = (int*)(cat + cat_e);                 // 2 layers x 256 ints
    const size_t need = (seq_e + h0_e + h1_e + cat_e) * sizeof(short) + 2048;
    if (ws_size < need) return;

    hipMemsetAsync(flags, 0, 2 * 256 * sizeof(int), stream);

    embed_kernel<<<BATCH, 256, 0, stream>>>(x, Wg, bg, Wl, bl, seq);

    repack_kernel<<<(int)((cat0_n + 255) / 256), 256, 0, stream>>>(Wih0, Whh0, cat, 256);
    lstm_fused_kernel<512, 264, 520><<<256, 512, 0, stream>>>(seq, cat, bih0, bhh0, h0, flags);

    repack_kernel<<<(int)((cat_e + 255) / 256), 256, 0, stream>>>(Wih1, Whh1, cat, 512);
    lstm_fused_kernel<768, 520, 512><<<256, 512, 0, stream>>>(h0, cat, bih1, bhh1, h1, flags + 256);

    lout_kernel<<<(BATCH * 60 + 255) / 256, 256, 0, stream>>>(h1, Wlp, blp, out);
    gout_kernel<<<(BATCH + 255) / 256, 256, 0, stream>>>(h1, Wgp, bgp, out);
}